// Round 10
// baseline (12117.767 us; speedup 1.0000x reference)
//
#include <hip/hip_runtime.h>
#include <hip/hip_cooperative_groups.h>
#include <hip/hip_fp16.h>

namespace cg = cooperative_groups;

#define TSTEP 128
#define LATD 256

// ---------------------------------------------------------------------------
// R17 = R16 (verified 11.86 ms) + LDS-pinned GRU weights.
// R16 counters: FETCH 35 MB/step ~= full fp16 weight set (28.5 MB) refetched
// EVERY step (per-XCD weight set 4.1 MB ~ L2 capacity; evicted by streaming
// act/partial traffic). Fix: each block pins its gru1+gru2 weight tiles
// (48+48 KB, staged ONCE prologue-side with the verified staging code) and
// keeps a 64 KB scratch for acts/reduce/p5/p6. LDS = 160 KB (full CU pool,
// 1 block/CU as before). Removes 24 MB/step weight fetch + per-phase gru
// weight staging. FMA loop/thread map identical to R16. Gru reduce: 2-round
// region reduce in scratch (regions [128thr][48]f), ksub0 stores final fp16
// partials directly (12 packed u64/thread, full sectors). p5/p6/combines/
// barrier/prologue verbatim R16 (run in scratch).
// Folds (verified R3-R16): Wvoih=(Wv@Wo)@Wih0, bfold=(bv@Wo+bo)@Wih0+bih0,
// WhW1=Wh@w1, bhw1=bh@w1+b1. Step = 8 phases.
// ---------------------------------------------------------------------------

typedef __attribute__((ext_vector_type(2))) unsigned long long u64x2;

struct P {
  const float *z, *w1, *b1, *w2, *b2, *Wv, *bv, *Wo, *bo;
  const float *Wih0, *Whh0, *bih0, *bhh0, *Wih1, *Whh1, *bih1, *bhh1, *Wh, *bh;
  float *out;
  __half *Wvoihh, *Whh0h, *Wih1h, *Whh1h, *WhW1h, *Whh, *w2h;
  float *part, *gin, *h1, *h2, *t1, *bvo, *bfold, *bhw1;
  __half *part16;  // alias of part region (fp16 partials in loop)
  unsigned *bar;   // leaves at i*32 (i<16), root at 512, flag at 544
};

__device__ __forceinline__ float ald(const float* p) {
  return __hip_atomic_load((float*)p, __ATOMIC_RELAXED, __HIP_MEMORY_SCOPE_AGENT);
}
__device__ __forceinline__ void ast(float* p, float v) {
  __hip_atomic_store(p, v, __ATOMIC_RELAXED, __HIP_MEMORY_SCOPE_AGENT);
}
__device__ __forceinline__ void ast32(unsigned* p, unsigned v) {
  __hip_atomic_store(p, v, __ATOMIC_RELAXED, __HIP_MEMORY_SCOPE_AGENT);
}
__device__ __forceinline__ void ast64(unsigned long long* p, unsigned long long v) {
  __hip_atomic_store(p, v, __ATOMIC_RELAXED, __HIP_MEMORY_SCOPE_AGENT);
}
__device__ __forceinline__ unsigned long long ald64(const unsigned long long* p) {
  return __hip_atomic_load((unsigned long long*)p, __ATOMIC_RELAXED,
                           __HIP_MEMORY_SCOPE_AGENT);
}
__device__ __forceinline__ float aldh(const __half* p) {
  unsigned short v = __hip_atomic_load((unsigned short*)p, __ATOMIC_RELAXED,
                                       __HIP_MEMORY_SCOPE_AGENT);
  __half h; *(unsigned short*)&h = v;
  return __half2float(h);
}
__device__ __forceinline__ unsigned pack2h(float x, float y) {
  union { unsigned u; __half h[2]; } c;
  c.h[0] = __float2half(x); c.h[1] = __float2half(y);
  return c.u;
}
__device__ __forceinline__ unsigned long long pack4h(float a, float b, float c,
                                                     float d) {
  union { unsigned long long q; __half h[4]; } u;
  u.h[0] = __float2half(a); u.h[1] = __float2half(b);
  u.h[2] = __float2half(c); u.h[3] = __float2half(d);
  return u.q;
}
__device__ __forceinline__ unsigned long long f4h4(float4 v) {
  union { unsigned long long q; __half h[4]; } c;
  c.h[0] = __float2half(v.x); c.h[1] = __float2half(v.y);
  c.h[2] = __float2half(v.z); c.h[3] = __float2half(v.w);
  return c.q;
}

// Fence-free hierarchical grid barrier (R7-proven; R12 version).
__device__ __forceinline__ void fastbar(unsigned* bar, unsigned& ep) {
  ++ep;
  __atomic_signal_fence(__ATOMIC_SEQ_CST);
  __builtin_amdgcn_s_waitcnt(0);
  __atomic_signal_fence(__ATOMIC_SEQ_CST);
  __syncthreads();
  if (threadIdx.x == 0) {
    unsigned* leaf = bar + (blockIdx.x & 15u) * 32u;
    unsigned a = atomicAdd(leaf, 1u);
    if (a == ep * 16u - 1u) {
      unsigned r = atomicAdd(bar + 512, 1u);
      if (r == ep * 16u - 1u)
        __hip_atomic_store(bar + 544, ep, __ATOMIC_RELAXED, __HIP_MEMORY_SCOPE_AGENT);
    }
    while (__hip_atomic_load(bar + 544, __ATOMIC_RELAXED, __HIP_MEMORY_SCOPE_AGENT) < ep)
      __builtin_amdgcn_s_sleep(1);
  }
  __syncthreads();
}

// ---- prologue helpers (256 blocks x 512 threads; identical to R16) --------
__device__ __forceinline__ void stv(float* p, float v) { *p = v; }
__device__ __forceinline__ void stv(__half* p, float v) { *p = __float2half(v); }

template <int J, int N, int CPT, typename OT>
__device__ void matmat(const float* __restrict__ A, const float* __restrict__ B,
                       OT* __restrict__ C) {
  const int tid = threadIdx.x;
  const int r = blockIdx.x * 4 + (tid >> 7);
  const int c0 = tid & 127;
  float acc[CPT];
#pragma unroll
  for (int i = 0; i < CPT; ++i) acc[i] = 0.f;
  const float* ar = A + (size_t)r * J;
#pragma unroll 2
  for (int j = 0; j < J; ++j) {
    float av = ar[j];
    const float* br = B + (size_t)j * N + c0;
#pragma unroll
    for (int i = 0; i < CPT; ++i) acc[i] = fmaf(av, br[i * 128], acc[i]);
  }
  OT* cr = C + (size_t)r * N + c0;
#pragma unroll
  for (int i = 0; i < CPT; ++i) stv(cr + (size_t)i * 128, acc[i]);
}

__device__ void cvt_copy(const float* __restrict__ s, __half* __restrict__ d,
                         int n4) {
  for (int i = (int)(blockIdx.x * 512u + threadIdx.x); i < n4; i += 131072)
    *(unsigned long long*)(d + (size_t)i * 4) = f4h4(*(const float4*)(s + (size_t)i * 4));
}

__device__ void vecmat(const float* __restrict__ v, const float* __restrict__ M,
                       const float* __restrict__ badd, float* __restrict__ outv,
                       int J, int N, int blk0, int nblk) {
  int b = (int)blockIdx.x;
  if (b < blk0 || b >= blk0 + nblk) return;
  int gid = (b - blk0) * 512 + threadIdx.x;
  if (gid >= N) return;
  float acc = 0.f;
#pragma unroll 4
  for (int j = 0; j < J; ++j) acc = fmaf(v[j], M[(size_t)j * N + gid], acc);
  outv[gid] = acc + badd[gid];
}

__device__ void gemv1024(const float* __restrict__ A, const float* __restrict__ W,
                         const float* __restrict__ bias, int K, int relu,
                         float* __restrict__ C, float* __restrict__ C2,
                         float* __restrict__ C3, float* red) {
  const int tid = threadIdx.x;
  const int m = tid & 63, w = tid >> 6;
  const int j = w & 3, hh = w >> 2;
  const int c = blockIdx.x * 4 + j;
  const int kh = K >> 1;
  const float* a = A + m + (hh * kh) * 64;
  const float* wp = W + c + (size_t)(hh * kh) * 1024;
  float acc = 0.f;
#pragma unroll 8
  for (int k = 0; k < kh; ++k) acc = fmaf(a[k * 64], wp[(size_t)k * 1024], acc);
  if (hh) red[j * 64 + m] = acc;
  __syncthreads();
  if (!hh) {
    float v = acc + red[j * 64 + m] + bias[c];
    if (relu) v = fmaxf(v, 0.f);
    C[c * 64 + m] = v;
    if (C2) C2[c * 64 + m] = v;
    if (C3) C3[c * 64 + m] = v;
  }
  __syncthreads();
}

// ---- pin one gru weight tile (256 rows x 96 cols fp16) into LDS planes ----
// Verified staging pattern from R12/R16: thread (k=tid>>1, hr=tid&1) moves
// 48 halves (12 u64 of the 24-u64 row): planeA [256][64]h, planeB [256][32]h.
__device__ void pin_w(const __half* __restrict__ W, int k0, int c0,
                      float* __restrict__ paf, float* __restrict__ pbf) {
  const int tid = threadIdx.x;
  const int k = tid >> 1, hr = tid & 1;
  const unsigned long long* Wr =
      (const unsigned long long*)(W + (size_t)(k0 + k) * 3072 + c0) + hr * 12;
  unsigned long long* pa = (unsigned long long*)paf + k * 16 + hr * 8;
  unsigned long long* pb = (unsigned long long*)pbf + k * 8 + hr * 4;
#pragma unroll
  for (int j = 0; j < 4; ++j) {
    unsigned long long q0 = Wr[j * 3];
    unsigned long long q1 = Wr[j * 3 + 1];
    unsigned long long q2 = Wr[j * 3 + 2];
    pa[j * 2] = q0; pa[j * 2 + 1] = q1; pb[j] = q2;
  }
}

// ---- GRU matmul (pinned weights): 256 blocks = 32 cg(96) x 8 K-slices ----
// Stage acts only (16384 f into scratch). FMA identical to R16 but weight
// pointers target pinned planes. Reduce: 2-round regions [128][48]f in
// scratch (acts dead); ksub0 stores final fp16 partials directly (12 u64).
__device__ __forceinline__ void gru_mm_p(const float* __restrict__ A,
                                         const __half* __restrict__ planeA,
                                         const __half* __restrict__ planeB,
                                         int s, int c0,
                                         __half* __restrict__ part16,
                                         float* __restrict__ scr) {
  const int tid = threadIdx.x;
  {  // stage acts (8192 u64)
    const unsigned long long* Ab = (const unsigned long long*)A;
    unsigned long long* Sb = (unsigned long long*)scr;
#pragma unroll
    for (int i = 0; i < 16; ++i) Sb[tid + i * 512] = ald64(Ab + tid + i * 512);
  }
  __syncthreads();

  const int ksub = tid >> 7, u = tid & 127;
  const int mq = u & 15, cg = u >> 4;
  float acc[48];
#pragma unroll
  for (int j = 0; j < 48; ++j) acc[j] = 0.f;
  const float* ap = scr + (size_t)(ksub * 64) * 64 + mq * 4;
  const __half* wa = planeA + (size_t)(ksub * 64) * 64 + cg * 8;
  const __half* wb = planeB + (size_t)(ksub * 64) * 32 + cg * 4;
#pragma unroll 2
  for (int k = 0; k < 64; ++k) {
    float4 a4 = *(const float4*)(ap + k * 64);
    union { u64x2 v; __half h[8]; } ua;
    ua.v = *(const u64x2*)(wa + k * 64);
    union { unsigned long long v; __half h[4]; } ub;
    ub.v = *(const unsigned long long*)(wb + k * 32);
#pragma unroll
    for (int c = 0; c < 8; ++c) {
      float wf = __half2float(ua.h[c]);
      acc[c * 4 + 0] = fmaf(a4.x, wf, acc[c * 4 + 0]);
      acc[c * 4 + 1] = fmaf(a4.y, wf, acc[c * 4 + 1]);
      acc[c * 4 + 2] = fmaf(a4.z, wf, acc[c * 4 + 2]);
      acc[c * 4 + 3] = fmaf(a4.w, wf, acc[c * 4 + 3]);
    }
#pragma unroll
    for (int c = 0; c < 4; ++c) {
      float wf = __half2float(ub.h[c]);
      acc[32 + c * 4 + 0] = fmaf(a4.x, wf, acc[32 + c * 4 + 0]);
      acc[32 + c * 4 + 1] = fmaf(a4.y, wf, acc[32 + c * 4 + 1]);
      acc[32 + c * 4 + 2] = fmaf(a4.z, wf, acc[32 + c * 4 + 2]);
      acc[32 + c * 4 + 3] = fmaf(a4.w, wf, acc[32 + c * 4 + 3]);
    }
  }
  // ---- 2-round reduce in scratch (acts dead after this sync) ----
  __syncthreads();
  float* regA = scr;            // [128][48]
  float* regB = scr + 6144;     // [128][48]
  auto wr48 = [&](float* r0) {
    float4* rp = (float4*)(r0 + (size_t)u * 48);
#pragma unroll
    for (int j = 0; j < 12; ++j)
      rp[j] = make_float4(acc[4 * j], acc[4 * j + 1], acc[4 * j + 2], acc[4 * j + 3]);
  };
  auto add48 = [&](const float* r0) {
    const float4* rp = (const float4*)(r0 + (size_t)u * 48);
#pragma unroll
    for (int j = 0; j < 12; ++j) {
      float4 r4 = rp[j];
      acc[4 * j] += r4.x; acc[4 * j + 1] += r4.y;
      acc[4 * j + 2] += r4.z; acc[4 * j + 3] += r4.w;
    }
  };
  if (ksub == 1) wr48(regA);
  if (ksub == 3) wr48(regB);
  __syncthreads();
  if (ksub == 0) add48(regA);
  if (ksub == 2) add48(regB);
  __syncthreads();
  if (ksub == 2) wr48(regA);
  __syncthreads();
  if (ksub == 0) {
    add48(regA);
    __half* pbase = part16 + ((size_t)s * 3072 + c0 + (size_t)cg * 12) * 64 + mq * 4;
#pragma unroll
    for (int c = 0; c < 8; ++c)
      ast64((unsigned long long*)(pbase + (size_t)c * 64),
            pack4h(acc[c * 4], acc[c * 4 + 1], acc[c * 4 + 2], acc[c * 4 + 3]));
#pragma unroll
    for (int c = 0; c < 4; ++c)
      ast64((unsigned long long*)(pbase + (size_t)(8 + c) * 64),
            pack4h(acc[32 + c * 4], acc[32 + c * 4 + 1],
                   acc[32 + c * 4 + 2], acc[32 + c * 4 + 3]));
  }
}

// GRU combine: 8 fp16 K-slices (0-3 x-part, 4-7 h-part). 256 blocks, 256 thr.
__device__ __forceinline__ void gru_comb(const __half* __restrict__ part16,
                                         const float* __restrict__ bx,
                                         const float* __restrict__ bm,
                                         float* __restrict__ h) {
  const int tid = threadIdx.x, bid = blockIdx.x;
  if (tid >= 256) return;
  const int c = bid * 4 + (tid >> 6), m = tid & 63;
  float ra = 0.f, za = 0.f, ia = 0.f, na = 0.f;
#pragma unroll
  for (int s = 0; s < 8; ++s) {
    const __half* ps = part16 + (size_t)s * 3072 * 64;
    ra += aldh(ps + (size_t)c * 64 + m);
    za += aldh(ps + (size_t)(1024 + c) * 64 + m);
    float nv = aldh(ps + (size_t)(2048 + c) * 64 + m);
    if (s < 4) ia += nv; else na += nv;
  }
  float r  = 1.f / (1.f + expf(-(ra + bx[c] + bm[c])));
  float zg = 1.f / (1.f + expf(-(za + bx[1024 + c] + bm[1024 + c])));
  float nn = tanhf(ia + bx[2048 + c] + r * (na + bm[2048 + c]));
  float hp = ald(h + (size_t)c * 64 + m);
  ast(h + (size_t)c * 64 + m, (1.f - zg) * nn + zg * hp);
}

// ---- P5 (verbatim R16, runs in scratch): C=1280, 32 groups(40) x 8 slices.
__device__ __forceinline__ void p5_mm(const __half* __restrict__ WhW1,
                                      const __half* __restrict__ Whd,
                                      const float* __restrict__ h2,
                                      __half* __restrict__ part16,
                                      float* __restrict__ sm) {
  const int tid = threadIdx.x, bid = blockIdx.x;
  const int g = bid >> 3, s = bid & 7;
  const int c0 = g * 40;
  const int k0 = s * 128;
  const float* A = h2 + (size_t)k0 * 64;

  {  // stage acts (4096 dw)
    const unsigned long long* Ab = (const unsigned long long*)A;
    unsigned long long* Sb = (unsigned long long*)sm;
#pragma unroll
    for (int i = 0; i < 8; ++i) Sb[tid + i * 512] = ald64(Ab + tid + i * 512);
  }
  {  // stage weights: 1024 (row,grp) pairs, 5 scalar halves each, padded 8
    __half* Sw = (__half*)(sm + 8192);
#pragma unroll
    for (int r = 0; r < 2; ++r) {
      int i2 = tid + r * 512;
      int row = i2 & 127, grp = i2 >> 7;
      const int gcb = c0 + grp * 5;
      __half* dst = Sw + row * 64 + grp * 8;
#pragma unroll
      for (int j = 0; j < 5; ++j) {
        int gc = gcb + j;
        dst[j] = (gc < 1024) ? WhW1[(size_t)(k0 + row) * 1024 + gc]
                             : Whd[(size_t)(k0 + row) * 256 + (gc - 1024)];
      }
    }
  }
  __syncthreads();

  const int ksub = tid >> 7, u = tid & 127;
  const int mq = u & 15, cg = u >> 4;
  float acc[20];
#pragma unroll
  for (int j = 0; j < 20; ++j) acc[j] = 0.f;
  const float* ap = sm + (size_t)(ksub * 32) * 64 + mq * 4;
  const __half* wp = (const __half*)(sm + 8192) + (size_t)(ksub * 32) * 64 + cg * 8;
#pragma unroll 4
  for (int k = 0; k < 32; ++k) {
    float4 a4 = *(const float4*)(ap + k * 64);
    union { u64x2 v; __half h[8]; } uw;
    uw.v = *(const u64x2*)(wp + k * 64);
#pragma unroll
    for (int cc = 0; cc < 5; ++cc) {
      float wf = __half2float(uw.h[cc]);
      acc[cc * 4 + 0] = fmaf(a4.x, wf, acc[cc * 4 + 0]);
      acc[cc * 4 + 1] = fmaf(a4.y, wf, acc[cc * 4 + 1]);
      acc[cc * 4 + 2] = fmaf(a4.z, wf, acc[cc * 4 + 2]);
      acc[cc * 4 + 3] = fmaf(a4.w, wf, acc[cc * 4 + 3]);
    }
  }
  __syncthreads();
  float* red = sm;   // 4 regions x 2560 floats, layout = col_local*64 + m
  {
    float* rp = red + (size_t)ksub * 2560 + (size_t)cg * 5 * 64 + mq * 4;
#pragma unroll
    for (int cc = 0; cc < 5; ++cc)
      *(float4*)(rp + (size_t)cc * 64) =
          make_float4(acc[cc * 4], acc[cc * 4 + 1], acc[cc * 4 + 2], acc[cc * 4 + 3]);
  }
  __syncthreads();
  {
    __half* pbase = part16 + ((size_t)s * 1280 + c0) * 64;   // 2560 contiguous
#pragma unroll
    for (int ps5 = 0; ps5 < 3; ++ps5) {
      int idx = ps5 * 1024 + tid * 2;
      if (idx < 2560) {
        float2 a0 = *(const float2*)(red + idx);
        float2 a1 = *(const float2*)(red + 2560 + idx);
        float2 a2 = *(const float2*)(red + 5120 + idx);
        float2 a3 = *(const float2*)(red + 7680 + idx);
        float v0 = (a0.x + a1.x) + (a2.x + a3.x);
        float v1 = (a0.y + a1.y) + (a2.y + a3.y);
        ast32((unsigned*)(pbase + idx), pack2h(v0, v1));
      }
    }
  }
}

// P5 combine: t1 cols 0..1023 (tid<256), out cols 1024..1279 (tid 256..319).
__device__ __forceinline__ void p5b(const __half* __restrict__ part16,
                                    const float* __restrict__ bhw1,
                                    const float* __restrict__ bh,
                                    float* __restrict__ t1, float* __restrict__ out,
                                    int t) {
  const int tid = threadIdx.x, bid = blockIdx.x;
  if (tid < 256) {
    const int c = bid * 4 + (tid >> 6), m = tid & 63;
    float v = 0.f;
#pragma unroll
    for (int s = 0; s < 8; ++s) v += aldh(part16 + ((size_t)s * 1280 + c) * 64 + m);
    ast(t1 + (size_t)c * 64 + m, fmaxf(v + bhw1[c], 0.f));
  } else if (tid < 320) {
    const int m = tid - 256, c2 = bid;
    float v = 0.f;
#pragma unroll
    for (int s = 0; s < 8; ++s)
      v += aldh(part16 + ((size_t)s * 1280 + 1024 + c2) * 64 + m);
    out[(size_t)(m * TSTEP + t) * LATD + c2] = v + bh[c2];
  }
}

// P6 (verbatim R16, runs in scratch).
__device__ __forceinline__ void p6_mm(const __half* __restrict__ w2h,
                                      const float* __restrict__ t1,
                                      __half* __restrict__ part16,
                                      float* __restrict__ sm) {
  const int tid = threadIdx.x;
  const int bid = blockIdx.x;
  const int g = bid >> 3, s = bid & 7;
  const int c0 = g * 32;
  const int k0 = s * 128;
  const float* A = t1 + (size_t)k0 * 64;

  {  // stage acts (4096 dw)
    const unsigned long long* Ab = (const unsigned long long*)A;
    unsigned long long* Sb = (unsigned long long*)sm;
#pragma unroll
    for (int i = 0; i < 8; ++i) Sb[tid + i * 512] = ald64(Ab + tid + i * 512);
  }
  {  // stage weights: 1024 8B-chunks (4 halves each)
    unsigned long long* Sw = (unsigned long long*)(sm + 8192);
#pragma unroll
    for (int i = 0; i < 2; ++i) {
      int q = tid + i * 512;
      int k = q >> 3, cq = q & 7;
      Sw[k * 8 + cq] =
          *(const unsigned long long*)(w2h + (size_t)(k0 + k) * 1024 + c0 + cq * 4);
    }
  }
  __syncthreads();

  const int ksub = tid >> 7, u = tid & 127;
  const int mq = u & 15, cg = u >> 4;
  float acc[16];
#pragma unroll
  for (int j = 0; j < 16; ++j) acc[j] = 0.f;
  const float* ap = sm + (size_t)(ksub * 32) * 64 + mq * 4;
  const __half* wp = (const __half*)(sm + 8192) + (size_t)(ksub * 32) * 32 + cg * 4;
#pragma unroll 4
  for (int k = 0; k < 32; ++k) {
    float4 a4 = *(const float4*)(ap + k * 64);
    union { unsigned long long v; __half h[4]; } ub;
    ub.v = *(const unsigned long long*)(wp + k * 32);
#pragma unroll
    for (int c = 0; c < 4; ++c) {
      float wf = __half2float(ub.h[c]);
      acc[c * 4 + 0] = fmaf(a4.x, wf, acc[c * 4 + 0]);
      acc[c * 4 + 1] = fmaf(a4.y, wf, acc[c * 4 + 1]);
      acc[c * 4 + 2] = fmaf(a4.z, wf, acc[c * 4 + 2]);
      acc[c * 4 + 3] = fmaf(a4.w, wf, acc[c * 4 + 3]);
    }
  }
  __syncthreads();
  float* red = sm;   // 4 regions x 2048 floats
  {
    float* rp = red + (size_t)ksub * 2048 + (size_t)cg * 4 * 64 + mq * 4;
#pragma unroll
    for (int c = 0; c < 4; ++c)
      *(float4*)(rp + (size_t)c * 64) =
          make_float4(acc[c * 4], acc[c * 4 + 1], acc[c * 4 + 2], acc[c * 4 + 3]);
  }
  __syncthreads();
  {
    __half* pbase = part16 + ((size_t)s * 1024 + c0) * 64;   // 2048 contiguous
#pragma unroll
    for (int ps5 = 0; ps5 < 2; ++ps5) {
      int idx = ps5 * 1024 + tid * 2;
      float2 a0 = *(const float2*)(red + idx);
      float2 a1 = *(const float2*)(red + 2048 + idx);
      float2 a2 = *(const float2*)(red + 4096 + idx);
      float2 a3 = *(const float2*)(red + 6144 + idx);
      float v0 = (a0.x + a1.x) + (a2.x + a3.x);
      float v1 = (a0.y + a1.y) + (a2.y + a3.y);
      ast32((unsigned*)(pbase + idx), pack2h(v0, v1));
    }
  }
}

__device__ __forceinline__ void p6b(const __half* __restrict__ part16,
                                    const float* __restrict__ b2,
                                    float* __restrict__ gin) {
  const int tid = threadIdx.x, bid = blockIdx.x;
  if (tid >= 256) return;
  const int c = bid * 4 + (tid >> 6), m = tid & 63;
  float v = 0.f;
#pragma unroll
  for (int s = 0; s < 8; ++s) v += aldh(part16 + ((size_t)s * 1024 + c) * 64 + m);
  ast(gin + (size_t)c * 64 + m, fmaxf(v + b2[c], 0.f));
}

__global__ __launch_bounds__(512, 1) void persist(P p) {
  cg::grid_group grid = cg::this_grid();
  // 160 KB: pinned gru1 planeA [0,8192) planeB [8192,12288) | gru2 planeA
  // [12288,20480) planeB [20480,24576) | scratch [24576,40960) = 64 KB
  // (gru acts [256][64]f32 exactly; p5/p6 acts+weights+reduce; gemv red).
  __shared__ float sm[40960];
  float* const SCR = sm + 24576;
  unsigned ep = 0;

  // ---- prologue (4 slow cg syncs flush prologue's normal stores) ----
  if (blockIdx.x == 0) {
    for (int i = threadIdx.x; i < 1024; i += 512) p.bar[i] = 0u;
  }
  if (threadIdx.x < 64) {  // z transpose -> h1 region (consumed pre-overwrite)
    int i = blockIdx.x * 64 + threadIdx.x;
    int m = i >> 8, l = i & 255;
    p.h1[l * 64 + m] = p.z[i];
  }
  matmat<1024, 1024, 8>(p.Wv, p.Wo, p.part);            // Wvo (fp32 temp)
  vecmat(p.bh, p.w1, p.b1, p.bhw1, 256, 1024, 0, 2);
  vecmat(p.bv, p.Wo, p.bo, p.bvo, 1024, 1024, 2, 2);
  cvt_copy(p.Whh0, p.Whh0h, 786432);                    // raw weights -> fp16
  cvt_copy(p.Wih1, p.Wih1h, 786432);
  cvt_copy(p.Whh1, p.Whh1h, 786432);
  cvt_copy(p.w2,   p.w2h,   262144);
  cvt_copy(p.Wh,   p.Whh,   65536);
  grid.sync();
  matmat<1024, 3072, 24>(p.part, p.Wih0, p.Wvoihh);     // Wvoih -> fp16 direct
  matmat<256, 1024, 8>(p.Wh, p.w1, p.WhW1h);            // WhW1 -> fp16 direct
  vecmat(p.bvo, p.Wih0, p.bih0, p.bfold, 1024, 3072, 0, 6);
  grid.sync();
  gemv1024(p.h1, p.w1, p.b1, 256, 1, p.t1, nullptr, nullptr, SCR);
  grid.sync();
  gemv1024(p.t1, p.w2, p.b2, 1024, 0, p.h1, p.h2, p.gin, SCR);
  grid.sync();

  // ---- pin gru weight tiles once (reused for all 128 steps) ----
  const int s0 = blockIdx.x & 7, g0 = blockIdx.x >> 3;
  const int c00 = g0 * 96, k00 = (s0 & 3) * 256;
  pin_w((s0 < 4 ? p.Wvoihh : p.Whh0h), k00, c00, sm, sm + 8192);
  pin_w((s0 < 4 ? p.Wih1h  : p.Whh1h), k00, c00, sm + 12288, sm + 20480);
  __syncthreads();

  // ---- time loop: 8 fence-free phases/step ----
  for (int t = 0; t < TSTEP; ++t) {
    gru_mm_p((s0 < 4 ? p.gin : p.h1) + (size_t)k00 * 64, (const __half*)sm,
             (const __half*)(sm + 8192), s0, c00, p.part16, SCR);
    fastbar(p.bar, ep);
    gru_comb(p.part16, p.bfold, p.bhh0, p.h1);            fastbar(p.bar, ep);
    gru_mm_p((s0 < 4 ? p.h1 : p.h2) + (size_t)k00 * 64, (const __half*)(sm + 12288),
             (const __half*)(sm + 20480), s0, c00, p.part16, SCR);
    fastbar(p.bar, ep);
    gru_comb(p.part16, p.bih1, p.bhh1, p.h2);             fastbar(p.bar, ep);
    p5_mm(p.WhW1h, p.Whh, p.h2, p.part16, SCR);           fastbar(p.bar, ep);
    p5b(p.part16, p.bhw1, p.bh, p.t1, p.out, t);          fastbar(p.bar, ep);
    p6_mm(p.w2h, p.t1, p.part16, SCR);                    fastbar(p.bar, ep);
    p6b(p.part16, p.b2, p.gin);                           fastbar(p.bar, ep);
  }
}

// ---------------------------------------------------------------------------
// Fallback path (round-2 verified multi-kernel, fp32 — unchanged).
// ---------------------------------------------------------------------------
__global__ void fb_transpose(const float* __restrict__ z, float* __restrict__ zT) {
  int i = blockIdx.x * 256 + threadIdx.x;
  int m = i >> 8, l = i & 255;
  zT[l * 64 + m] = z[i];
}
__global__ void fb_copy2(const float* __restrict__ s, float* __restrict__ d1,
                         float* __restrict__ d2) {
  int i = blockIdx.x * 256 + threadIdx.x;
  float v = s[i]; d1[i] = v; d2[i] = v;
}
template <int ACT>
__global__ void fb_gemm(const float* __restrict__ A_T, const float* __restrict__ W,
                        const float* __restrict__ bias, float* __restrict__ C_T,
                        int K, int N, float* __restrict__ outp, int tstep) {
  const int m = threadIdx.x & 63;
  const int wv = threadIdx.x >> 6;
  const int c = blockIdx.x * 4 + wv;
  float acc0 = 0.f, acc1 = 0.f;
  const float* ap = A_T + m;
  const float* wp = W + c;
#pragma unroll 4
  for (int k = 0; k + 1 < K; k += 2) {
    acc0 = fmaf(ap[k * 64], wp[(size_t)k * N], acc0);
    acc1 = fmaf(ap[(k + 1) * 64], wp[(size_t)(k + 1) * N], acc1);
  }
  float v0 = acc0 + acc1 + bias[c];
  if (ACT) v0 = fmaxf(v0, 0.f);
  C_T[c * 64 + m] = v0;
  if (outp != nullptr) outp[(size_t)(m * TSTEP + tstep) * LATD + c] = v0;
}
__global__ void fb_gru(const float* __restrict__ xT, const float* __restrict__ hT,
                       const float* __restrict__ Wih, const float* __restrict__ Whh,
                       const float* __restrict__ bih, const float* __restrict__ bhh,
                       float* __restrict__ hnT) {
  const int m = threadIdx.x & 63;
  const int wv = threadIdx.x >> 6;
  const int c = blockIdx.x * 4 + wv;
  float racc = 0, zacc = 0, iacc = 0, nacc = 0;
  const float* xp = xT + m;
  const float* hp = hT + m;
  const float* wi = Wih + c;
  const float* wh = Whh + c;
#pragma unroll 2
  for (int k = 0; k < 1024; ++k) {
    float a = xp[k * 64];
    float h = hp[k * 64];
    const float* wik = wi + (size_t)k * 3072;
    const float* whk = wh + (size_t)k * 3072;
    racc = fmaf(a, wik[0], racc); racc = fmaf(h, whk[0], racc);
    zacc = fmaf(a, wik[1024], zacc); zacc = fmaf(h, whk[1024], zacc);
    iacc = fmaf(a, wik[2048], iacc);
    nacc = fmaf(h, whk[2048], nacc);
  }
  float r = 1.f / (1.f + expf(-(racc + bih[c] + bhh[c])));
  float zg = 1.f / (1.f + expf(-(zacc + bih[1024 + c] + bhh[1024 + c])));
  float nn = tanhf(iacc + bih[2048 + c] + r * (nacc + bhh[2048 + c]));
  hnT[c * 64 + m] = (1.f - zg) * nn + zg * hT[c * 64 + m];
}

extern "C" void kernel_launch(void* const* d_in, const int* in_sizes, int n_in,
                              void* d_out, int out_size, void* d_ws, size_t ws_size,
                              hipStream_t stream) {
  const float* z_start = (const float*)d_in[0];
  const float* w1 = (const float*)d_in[2];
  const float* b1 = (const float*)d_in[3];
  const float* w2 = (const float*)d_in[4];
  const float* b2 = (const float*)d_in[5];
  const float* Wv = (const float*)d_in[10];
  const float* bv = (const float*)d_in[11];
  const float* Wo = (const float*)d_in[12];
  const float* bo = (const float*)d_in[13];
  const float* Wih0 = (const float*)d_in[14];
  const float* Whh0 = (const float*)d_in[15];
  const float* bih0 = (const float*)d_in[16];
  const float* bhh0 = (const float*)d_in[17];
  const float* Wih1 = (const float*)d_in[18];
  const float* Whh1 = (const float*)d_in[19];
  const float* bih1 = (const float*)d_in[20];
  const float* bhh1 = (const float*)d_in[21];
  const float* Wh = (const float*)d_in[22];
  const float* bh = (const float*)d_in[23];
  float* out = (float*)d_out;
  float* ws = (float*)d_ws;

  // floats: 4x1572864 (fp16 wbufs) + part 1572864 (Wvo fp32 temp in
  // prologue; 8x3072x64 fp16 partials in loop) + 524288x2 (WhW1_h,w2_h) +
  // 131072 (Wh_h) + 4x65536 acts + 5120 small + 1024 bar
  const size_t need = (size_t)9312256 * 4;
  if (ws_size >= need) {
    P p;
    p.z = z_start; p.w1 = w1; p.b1 = b1; p.w2 = w2; p.b2 = b2;
    p.Wv = Wv; p.bv = bv; p.Wo = Wo; p.bo = bo;
    p.Wih0 = Wih0; p.Whh0 = Whh0; p.bih0 = bih0; p.bhh0 = bhh0;
    p.Wih1 = Wih1; p.Whh1 = Whh1; p.bih1 = bih1; p.bhh1 = bhh1;
    p.Wh = Wh; p.bh = bh; p.out = out;
    float* q = ws;
    p.Wvoihh = (__half*)q; q += 1572864;   // 1024x3072 halves
    p.Whh0h  = (__half*)q; q += 1572864;
    p.Wih1h  = (__half*)q; q += 1572864;
    p.Whh1h  = (__half*)q; q += 1572864;
    p.WhW1h  = (__half*)q; q += 524288;    // 1024x1024 halves
    p.Whh    = (__half*)q; q += 131072;    // 1024x256 halves
    p.w2h    = (__half*)q; q += 524288;
    p.part = q; q += 1572864;   // Wvo fp32 temp in prologue; fp16 parts loop
    p.part16 = (__half*)p.part;
    p.gin = q; q += 65536;
    p.h1 = q; q += 65536;       // also zT during prologue
    p.h2 = q; q += 65536;
    p.t1 = q; q += 65536;
    p.bvo = q; q += 1024;
    p.bfold = q; q += 3072;
    p.bhw1 = q; q += 1024;
    p.bar = (unsigned*)q; q += 1024;
    void* args[] = { &p };
    hipError_t e = hipLaunchCooperativeKernel((const void*)persist, dim3(256),
                                              dim3(512), args, 0, stream);
    if (e == hipSuccess) return;
  }

  // -------- fallback: verified round-2 path --------
  float* zsT = ws;
  float* vT = zsT + 16384;
  float* xaT = vT + 65536;
  float* t1T = xaT + 65536;
  float* ginT = t1T + 65536;
  float* nzT = ginT + 65536;
  float* h1T = nzT + 16384;
  float* h2T = h1T + 2 * 65536;

  fb_transpose<<<64, 256, 0, stream>>>(z_start, zsT);
  fb_gemm<1><<<256, 256, 0, stream>>>(zsT, w1, b1, t1T, 256, 1024, nullptr, 0);
  fb_gemm<0><<<256, 256, 0, stream>>>(t1T, w2, b2, h1T, 1024, 1024, nullptr, 0);
  fb_copy2<<<256, 256, 0, stream>>>(h1T, h2T, ginT);
  for (int t = 0; t < TSTEP; ++t) {
    float* h1p = h1T + (t & 1) * 65536;
    float* h1n = h1T + ((t + 1) & 1) * 65536;
    float* h2p = h2T + (t & 1) * 65536;
    float* h2n = h2T + ((t + 1) & 1) * 65536;
    fb_gemm<0><<<256, 256, 0, stream>>>(ginT, Wv, bv, vT, 1024, 1024, nullptr, 0);
    fb_gemm<0><<<256, 256, 0, stream>>>(vT, Wo, bo, xaT, 1024, 1024, nullptr, 0);
    fb_gru<<<256, 256, 0, stream>>>(xaT, h1p, Wih0, Whh0, bih0, bhh0, h1n);
    fb_gru<<<256, 256, 0, stream>>>(h1n, h2p, Wih1, Whh1, bih1, bhh1, h2n);
    fb_gemm<0><<<64, 256, 0, stream>>>(h2n, Wh, bh, nzT, 1024, 256, out, t);
    fb_gemm<1><<<256, 256, 0, stream>>>(nzT, w1, b1, t1T, 256, 1024, nullptr, 0);
    fb_gemm<1><<<256, 256, 0, stream>>>(t1T, w2, b2, ginT, 1024, 1024, nullptr, 0);
  }
}

// Round 11
// 11659.433 us; speedup vs baseline: 1.0393x; 1.0393x over previous
//
#include <hip/hip_runtime.h>
#include <hip/hip_cooperative_groups.h>
#include <hip/hip_fp16.h>

namespace cg = cooperative_groups;

#define TSTEP 128
#define LATD 256

// ---------------------------------------------------------------------------
// R18 = R17 pinned-gru-weights + R16's conflict-free reduce/epilogue.
// R17 post-mortem: FETCH -6.4 MB/step (pinning works, though most fetch is
// amplified act reads, not weights) BUT bank conflicts 1.3e8 -> 2.3e8: the
// u*48-stride reduce (48 mod 32 = 16 -> 16-way) + ksub0-only strided ast64
// final store (partial sectors) ate the win. Fix: part-linear regions
// (col*64+m, float4 stride-64, conflict-free) + dense all-512-thread fp16
// epilogue (R16-verified), in a 3-sync 2+merge scheme that fits the 16K-f
// scratch: ksub1->A, ksub3->B; ksub0 +=A,->A; ksub2 +=B,->B; dense A+B.
// Everything else verbatim R17 (p5/p6/combines/barrier/prologue).
// Folds (verified R3-R17): Wvoih=(Wv@Wo)@Wih0, bfold=(bv@Wo+bo)@Wih0+bih0,
// WhW1=Wh@w1, bhw1=bh@w1+b1. Step = 8 phases.
// ---------------------------------------------------------------------------

typedef __attribute__((ext_vector_type(2))) unsigned long long u64x2;

struct P {
  const float *z, *w1, *b1, *w2, *b2, *Wv, *bv, *Wo, *bo;
  const float *Wih0, *Whh0, *bih0, *bhh0, *Wih1, *Whh1, *bih1, *bhh1, *Wh, *bh;
  float *out;
  __half *Wvoihh, *Whh0h, *Wih1h, *Whh1h, *WhW1h, *Whh, *w2h;
  float *part, *gin, *h1, *h2, *t1, *bvo, *bfold, *bhw1;
  __half *part16;  // alias of part region (fp16 partials in loop)
  unsigned *bar;   // leaves at i*32 (i<16), root at 512, flag at 544
};

__device__ __forceinline__ float ald(const float* p) {
  return __hip_atomic_load((float*)p, __ATOMIC_RELAXED, __HIP_MEMORY_SCOPE_AGENT);
}
__device__ __forceinline__ void ast(float* p, float v) {
  __hip_atomic_store(p, v, __ATOMIC_RELAXED, __HIP_MEMORY_SCOPE_AGENT);
}
__device__ __forceinline__ void ast32(unsigned* p, unsigned v) {
  __hip_atomic_store(p, v, __ATOMIC_RELAXED, __HIP_MEMORY_SCOPE_AGENT);
}
__device__ __forceinline__ unsigned long long ald64(const unsigned long long* p) {
  return __hip_atomic_load((unsigned long long*)p, __ATOMIC_RELAXED,
                           __HIP_MEMORY_SCOPE_AGENT);
}
__device__ __forceinline__ float aldh(const __half* p) {
  unsigned short v = __hip_atomic_load((unsigned short*)p, __ATOMIC_RELAXED,
                                       __HIP_MEMORY_SCOPE_AGENT);
  __half h; *(unsigned short*)&h = v;
  return __half2float(h);
}
__device__ __forceinline__ unsigned pack2h(float x, float y) {
  union { unsigned u; __half h[2]; } c;
  c.h[0] = __float2half(x); c.h[1] = __float2half(y);
  return c.u;
}
__device__ __forceinline__ unsigned long long f4h4(float4 v) {
  union { unsigned long long q; __half h[4]; } c;
  c.h[0] = __float2half(v.x); c.h[1] = __float2half(v.y);
  c.h[2] = __float2half(v.z); c.h[3] = __float2half(v.w);
  return c.q;
}

// Fence-free hierarchical grid barrier (R7-proven; R12 version).
__device__ __forceinline__ void fastbar(unsigned* bar, unsigned& ep) {
  ++ep;
  __atomic_signal_fence(__ATOMIC_SEQ_CST);
  __builtin_amdgcn_s_waitcnt(0);
  __atomic_signal_fence(__ATOMIC_SEQ_CST);
  __syncthreads();
  if (threadIdx.x == 0) {
    unsigned* leaf = bar + (blockIdx.x & 15u) * 32u;
    unsigned a = atomicAdd(leaf, 1u);
    if (a == ep * 16u - 1u) {
      unsigned r = atomicAdd(bar + 512, 1u);
      if (r == ep * 16u - 1u)
        __hip_atomic_store(bar + 544, ep, __ATOMIC_RELAXED, __HIP_MEMORY_SCOPE_AGENT);
    }
    while (__hip_atomic_load(bar + 544, __ATOMIC_RELAXED, __HIP_MEMORY_SCOPE_AGENT) < ep)
      __builtin_amdgcn_s_sleep(1);
  }
  __syncthreads();
}

// ---- prologue helpers (256 blocks x 512 threads; identical to R16/R17) ----
__device__ __forceinline__ void stv(float* p, float v) { *p = v; }
__device__ __forceinline__ void stv(__half* p, float v) { *p = __float2half(v); }

template <int J, int N, int CPT, typename OT>
__device__ void matmat(const float* __restrict__ A, const float* __restrict__ B,
                       OT* __restrict__ C) {
  const int tid = threadIdx.x;
  const int r = blockIdx.x * 4 + (tid >> 7);
  const int c0 = tid & 127;
  float acc[CPT];
#pragma unroll
  for (int i = 0; i < CPT; ++i) acc[i] = 0.f;
  const float* ar = A + (size_t)r * J;
#pragma unroll 2
  for (int j = 0; j < J; ++j) {
    float av = ar[j];
    const float* br = B + (size_t)j * N + c0;
#pragma unroll
    for (int i = 0; i < CPT; ++i) acc[i] = fmaf(av, br[i * 128], acc[i]);
  }
  OT* cr = C + (size_t)r * N + c0;
#pragma unroll
  for (int i = 0; i < CPT; ++i) stv(cr + (size_t)i * 128, acc[i]);
}

__device__ void cvt_copy(const float* __restrict__ s, __half* __restrict__ d,
                         int n4) {
  for (int i = (int)(blockIdx.x * 512u + threadIdx.x); i < n4; i += 131072)
    *(unsigned long long*)(d + (size_t)i * 4) = f4h4(*(const float4*)(s + (size_t)i * 4));
}

__device__ void vecmat(const float* __restrict__ v, const float* __restrict__ M,
                       const float* __restrict__ badd, float* __restrict__ outv,
                       int J, int N, int blk0, int nblk) {
  int b = (int)blockIdx.x;
  if (b < blk0 || b >= blk0 + nblk) return;
  int gid = (b - blk0) * 512 + threadIdx.x;
  if (gid >= N) return;
  float acc = 0.f;
#pragma unroll 4
  for (int j = 0; j < J; ++j) acc = fmaf(v[j], M[(size_t)j * N + gid], acc);
  outv[gid] = acc + badd[gid];
}

__device__ void gemv1024(const float* __restrict__ A, const float* __restrict__ W,
                         const float* __restrict__ bias, int K, int relu,
                         float* __restrict__ C, float* __restrict__ C2,
                         float* __restrict__ C3, float* red) {
  const int tid = threadIdx.x;
  const int m = tid & 63, w = tid >> 6;
  const int j = w & 3, hh = w >> 2;
  const int c = blockIdx.x * 4 + j;
  const int kh = K >> 1;
  const float* a = A + m + (hh * kh) * 64;
  const float* wp = W + c + (size_t)(hh * kh) * 1024;
  float acc = 0.f;
#pragma unroll 8
  for (int k = 0; k < kh; ++k) acc = fmaf(a[k * 64], wp[(size_t)k * 1024], acc);
  if (hh) red[j * 64 + m] = acc;
  __syncthreads();
  if (!hh) {
    float v = acc + red[j * 64 + m] + bias[c];
    if (relu) v = fmaxf(v, 0.f);
    C[c * 64 + m] = v;
    if (C2) C2[c * 64 + m] = v;
    if (C3) C3[c * 64 + m] = v;
  }
  __syncthreads();
}

// ---- pin one gru weight tile (256 rows x 96 cols fp16) into LDS planes ----
__device__ void pin_w(const __half* __restrict__ W, int k0, int c0,
                      float* __restrict__ paf, float* __restrict__ pbf) {
  const int tid = threadIdx.x;
  const int k = tid >> 1, hr = tid & 1;
  const unsigned long long* Wr =
      (const unsigned long long*)(W + (size_t)(k0 + k) * 3072 + c0) + hr * 12;
  unsigned long long* pa = (unsigned long long*)paf + k * 16 + hr * 8;
  unsigned long long* pb = (unsigned long long*)pbf + k * 8 + hr * 4;
#pragma unroll
  for (int j = 0; j < 4; ++j) {
    unsigned long long q0 = Wr[j * 3];
    unsigned long long q1 = Wr[j * 3 + 1];
    unsigned long long q2 = Wr[j * 3 + 2];
    pa[j * 2] = q0; pa[j * 2 + 1] = q1; pb[j] = q2;
  }
}

// ---- GRU matmul (pinned weights, R18 reduce) ------------------------------
// FMA identical to R16/R17. Reduce: part-linear regions A/B (col*64+m,
// conflict-free), 2+merge (3 syncs), dense all-thread fp16 epilogue.
__device__ __forceinline__ void gru_mm_p(const float* __restrict__ A,
                                         const __half* __restrict__ planeA,
                                         const __half* __restrict__ planeB,
                                         int s, int c0,
                                         __half* __restrict__ part16,
                                         float* __restrict__ scr) {
  const int tid = threadIdx.x;
  {  // stage acts (8192 u64)
    const unsigned long long* Ab = (const unsigned long long*)A;
    unsigned long long* Sb = (unsigned long long*)scr;
#pragma unroll
    for (int i = 0; i < 16; ++i) Sb[tid + i * 512] = ald64(Ab + tid + i * 512);
  }
  __syncthreads();

  const int ksub = tid >> 7, u = tid & 127;
  const int mq = u & 15, cg = u >> 4;
  float acc[48];
#pragma unroll
  for (int j = 0; j < 48; ++j) acc[j] = 0.f;
  const float* ap = scr + (size_t)(ksub * 64) * 64 + mq * 4;
  const __half* wa = planeA + (size_t)(ksub * 64) * 64 + cg * 8;
  const __half* wb = planeB + (size_t)(ksub * 64) * 32 + cg * 4;
#pragma unroll 2
  for (int k = 0; k < 64; ++k) {
    float4 a4 = *(const float4*)(ap + k * 64);
    union { u64x2 v; __half h[8]; } ua;
    ua.v = *(const u64x2*)(wa + k * 64);
    union { unsigned long long v; __half h[4]; } ub;
    ub.v = *(const unsigned long long*)(wb + k * 32);
#pragma unroll
    for (int c = 0; c < 8; ++c) {
      float wf = __half2float(ua.h[c]);
      acc[c * 4 + 0] = fmaf(a4.x, wf, acc[c * 4 + 0]);
      acc[c * 4 + 1] = fmaf(a4.y, wf, acc[c * 4 + 1]);
      acc[c * 4 + 2] = fmaf(a4.z, wf, acc[c * 4 + 2]);
      acc[c * 4 + 3] = fmaf(a4.w, wf, acc[c * 4 + 3]);
    }
#pragma unroll
    for (int c = 0; c < 4; ++c) {
      float wf = __half2float(ub.h[c]);
      acc[32 + c * 4 + 0] = fmaf(a4.x, wf, acc[32 + c * 4 + 0]);
      acc[32 + c * 4 + 1] = fmaf(a4.y, wf, acc[32 + c * 4 + 1]);
      acc[32 + c * 4 + 2] = fmaf(a4.z, wf, acc[32 + c * 4 + 2]);
      acc[32 + c * 4 + 3] = fmaf(a4.w, wf, acc[32 + c * 4 + 3]);
    }
  }
  // ---- R18 reduce: part-linear regions, 2+merge, dense epilogue ----
  __syncthreads();            // acts dead
  float* regA = scr;          // [6144] col_local*64 + m
  float* regB = scr + 6144;   // [6144]
  auto wrPL = [&](float* r0) {
    float* rp = r0 + (size_t)cg * 12 * 64 + mq * 4;
#pragma unroll
    for (int c = 0; c < 8; ++c)
      *(float4*)(rp + (size_t)c * 64) =
          make_float4(acc[c * 4], acc[c * 4 + 1], acc[c * 4 + 2], acc[c * 4 + 3]);
#pragma unroll
    for (int c = 0; c < 4; ++c)
      *(float4*)(rp + (size_t)(8 + c) * 64) =
          make_float4(acc[32 + c * 4], acc[32 + c * 4 + 1],
                      acc[32 + c * 4 + 2], acc[32 + c * 4 + 3]);
  };
  auto addPL = [&](const float* r0) {
    const float* rp = r0 + (size_t)cg * 12 * 64 + mq * 4;
#pragma unroll
    for (int c = 0; c < 8; ++c) {
      float4 r4 = *(const float4*)(rp + (size_t)c * 64);
      acc[c * 4] += r4.x; acc[c * 4 + 1] += r4.y;
      acc[c * 4 + 2] += r4.z; acc[c * 4 + 3] += r4.w;
    }
#pragma unroll
    for (int c = 0; c < 4; ++c) {
      float4 r4 = *(const float4*)(rp + (size_t)(8 + c) * 64);
      acc[32 + c * 4] += r4.x; acc[32 + c * 4 + 1] += r4.y;
      acc[32 + c * 4 + 2] += r4.z; acc[32 + c * 4 + 3] += r4.w;
    }
  };
  if (ksub == 1) wrPL(regA);
  if (ksub == 3) wrPL(regB);
  __syncthreads();
  if (ksub == 0) { addPL(regA); wrPL(regA); }
  if (ksub == 2) { addPL(regB); wrPL(regB); }
  __syncthreads();
  {
    __half* pbase = part16 + ((size_t)s * 3072 + c0) * 64;   // 6144 contiguous
#pragma unroll
    for (int ps5 = 0; ps5 < 6; ++ps5) {
      int idx = ps5 * 1024 + tid * 2;
      float2 a0 = *(const float2*)(regA + idx);
      float2 b0 = *(const float2*)(regB + idx);
      ast32((unsigned*)(pbase + idx), pack2h(a0.x + b0.x, a0.y + b0.y));
    }
  }
}

// GRU combine: 8 fp16 K-slices (0-3 x-part, 4-7 h-part). 256 blocks, 256 thr.
__device__ __forceinline__ void gru_comb(const __half* __restrict__ part16,
                                         const float* __restrict__ bx,
                                         const float* __restrict__ bm,
                                         float* __restrict__ h) {
  const int tid = threadIdx.x, bid = blockIdx.x;
  if (tid >= 256) return;
  const int c = bid * 4 + (tid >> 6), m = tid & 63;
  float ra = 0.f, za = 0.f, ia = 0.f, na = 0.f;
#pragma unroll
  for (int s = 0; s < 8; ++s) {
    const __half* ps = part16 + (size_t)s * 3072 * 64;
    ra += aldh(ps + (size_t)c * 64 + m);
    za += aldh(ps + (size_t)(1024 + c) * 64 + m);
    float nv = aldh(ps + (size_t)(2048 + c) * 64 + m);
    if (s < 4) ia += nv; else na += nv;
  }
  float r  = 1.f / (1.f + expf(-(ra + bx[c] + bm[c])));
  float zg = 1.f / (1.f + expf(-(za + bx[1024 + c] + bm[1024 + c])));
  float nn = tanhf(ia + bx[2048 + c] + r * (na + bm[2048 + c]));
  float hp = ald(h + (size_t)c * 64 + m);
  ast(h + (size_t)c * 64 + m, (1.f - zg) * nn + zg * hp);
}

// ---- P5 (verbatim R16/R17, runs in scratch) -------------------------------
__device__ __forceinline__ void p5_mm(const __half* __restrict__ WhW1,
                                      const __half* __restrict__ Whd,
                                      const float* __restrict__ h2,
                                      __half* __restrict__ part16,
                                      float* __restrict__ sm) {
  const int tid = threadIdx.x, bid = blockIdx.x;
  const int g = bid >> 3, s = bid & 7;
  const int c0 = g * 40;
  const int k0 = s * 128;
  const float* A = h2 + (size_t)k0 * 64;

  {  // stage acts (4096 dw)
    const unsigned long long* Ab = (const unsigned long long*)A;
    unsigned long long* Sb = (unsigned long long*)sm;
#pragma unroll
    for (int i = 0; i < 8; ++i) Sb[tid + i * 512] = ald64(Ab + tid + i * 512);
  }
  {  // stage weights: 1024 (row,grp) pairs, 5 scalar halves each, padded 8
    __half* Sw = (__half*)(sm + 8192);
#pragma unroll
    for (int r = 0; r < 2; ++r) {
      int i2 = tid + r * 512;
      int row = i2 & 127, grp = i2 >> 7;
      const int gcb = c0 + grp * 5;
      __half* dst = Sw + row * 64 + grp * 8;
#pragma unroll
      for (int j = 0; j < 5; ++j) {
        int gc = gcb + j;
        dst[j] = (gc < 1024) ? WhW1[(size_t)(k0 + row) * 1024 + gc]
                             : Whd[(size_t)(k0 + row) * 256 + (gc - 1024)];
      }
    }
  }
  __syncthreads();

  const int ksub = tid >> 7, u = tid & 127;
  const int mq = u & 15, cg = u >> 4;
  float acc[20];
#pragma unroll
  for (int j = 0; j < 20; ++j) acc[j] = 0.f;
  const float* ap = sm + (size_t)(ksub * 32) * 64 + mq * 4;
  const __half* wp = (const __half*)(sm + 8192) + (size_t)(ksub * 32) * 64 + cg * 8;
#pragma unroll 4
  for (int k = 0; k < 32; ++k) {
    float4 a4 = *(const float4*)(ap + k * 64);
    union { u64x2 v; __half h[8]; } uw;
    uw.v = *(const u64x2*)(wp + k * 64);
#pragma unroll
    for (int cc = 0; cc < 5; ++cc) {
      float wf = __half2float(uw.h[cc]);
      acc[cc * 4 + 0] = fmaf(a4.x, wf, acc[cc * 4 + 0]);
      acc[cc * 4 + 1] = fmaf(a4.y, wf, acc[cc * 4 + 1]);
      acc[cc * 4 + 2] = fmaf(a4.z, wf, acc[cc * 4 + 2]);
      acc[cc * 4 + 3] = fmaf(a4.w, wf, acc[cc * 4 + 3]);
    }
  }
  __syncthreads();
  float* red = sm;   // 4 regions x 2560 floats, layout = col_local*64 + m
  {
    float* rp = red + (size_t)ksub * 2560 + (size_t)cg * 5 * 64 + mq * 4;
#pragma unroll
    for (int cc = 0; cc < 5; ++cc)
      *(float4*)(rp + (size_t)cc * 64) =
          make_float4(acc[cc * 4], acc[cc * 4 + 1], acc[cc * 4 + 2], acc[cc * 4 + 3]);
  }
  __syncthreads();
  {
    __half* pbase = part16 + ((size_t)s * 1280 + c0) * 64;   // 2560 contiguous
#pragma unroll
    for (int ps5 = 0; ps5 < 3; ++ps5) {
      int idx = ps5 * 1024 + tid * 2;
      if (idx < 2560) {
        float2 a0 = *(const float2*)(red + idx);
        float2 a1 = *(const float2*)(red + 2560 + idx);
        float2 a2 = *(const float2*)(red + 5120 + idx);
        float2 a3 = *(const float2*)(red + 7680 + idx);
        float v0 = (a0.x + a1.x) + (a2.x + a3.x);
        float v1 = (a0.y + a1.y) + (a2.y + a3.y);
        ast32((unsigned*)(pbase + idx), pack2h(v0, v1));
      }
    }
  }
}

// P5 combine: t1 cols 0..1023 (tid<256), out cols 1024..1279 (tid 256..319).
__device__ __forceinline__ void p5b(const __half* __restrict__ part16,
                                    const float* __restrict__ bhw1,
                                    const float* __restrict__ bh,
                                    float* __restrict__ t1, float* __restrict__ out,
                                    int t) {
  const int tid = threadIdx.x, bid = blockIdx.x;
  if (tid < 256) {
    const int c = bid * 4 + (tid >> 6), m = tid & 63;
    float v = 0.f;
#pragma unroll
    for (int s = 0; s < 8; ++s) v += aldh(part16 + ((size_t)s * 1280 + c) * 64 + m);
    ast(t1 + (size_t)c * 64 + m, fmaxf(v + bhw1[c], 0.f));
  } else if (tid < 320) {
    const int m = tid - 256, c2 = bid;
    float v = 0.f;
#pragma unroll
    for (int s = 0; s < 8; ++s)
      v += aldh(part16 + ((size_t)s * 1280 + 1024 + c2) * 64 + m);
    out[(size_t)(m * TSTEP + t) * LATD + c2] = v + bh[c2];
  }
}

// P6 (verbatim R16/R17, runs in scratch).
__device__ __forceinline__ void p6_mm(const __half* __restrict__ w2h,
                                      const float* __restrict__ t1,
                                      __half* __restrict__ part16,
                                      float* __restrict__ sm) {
  const int tid = threadIdx.x;
  const int bid = blockIdx.x;
  const int g = bid >> 3, s = bid & 7;
  const int c0 = g * 32;
  const int k0 = s * 128;
  const float* A = t1 + (size_t)k0 * 64;

  {  // stage acts (4096 dw)
    const unsigned long long* Ab = (const unsigned long long*)A;
    unsigned long long* Sb = (unsigned long long*)sm;
#pragma unroll
    for (int i = 0; i < 8; ++i) Sb[tid + i * 512] = ald64(Ab + tid + i * 512);
  }
  {  // stage weights: 1024 8B-chunks (4 halves each)
    unsigned long long* Sw = (unsigned long long*)(sm + 8192);
#pragma unroll
    for (int i = 0; i < 2; ++i) {
      int q = tid + i * 512;
      int k = q >> 3, cq = q & 7;
      Sw[k * 8 + cq] =
          *(const unsigned long long*)(w2h + (size_t)(k0 + k) * 1024 + c0 + cq * 4);
    }
  }
  __syncthreads();

  const int ksub = tid >> 7, u = tid & 127;
  const int mq = u & 15, cg = u >> 4;
  float acc[16];
#pragma unroll
  for (int j = 0; j < 16; ++j) acc[j] = 0.f;
  const float* ap = sm + (size_t)(ksub * 32) * 64 + mq * 4;
  const __half* wp = (const __half*)(sm + 8192) + (size_t)(ksub * 32) * 32 + cg * 4;
#pragma unroll 4
  for (int k = 0; k < 32; ++k) {
    float4 a4 = *(const float4*)(ap + k * 64);
    union { unsigned long long v; __half h[4]; } ub;
    ub.v = *(const unsigned long long*)(wp + k * 32);
#pragma unroll
    for (int c = 0; c < 4; ++c) {
      float wf = __half2float(ub.h[c]);
      acc[c * 4 + 0] = fmaf(a4.x, wf, acc[c * 4 + 0]);
      acc[c * 4 + 1] = fmaf(a4.y, wf, acc[c * 4 + 1]);
      acc[c * 4 + 2] = fmaf(a4.z, wf, acc[c * 4 + 2]);
      acc[c * 4 + 3] = fmaf(a4.w, wf, acc[c * 4 + 3]);
    }
  }
  __syncthreads();
  float* red = sm;   // 4 regions x 2048 floats
  {
    float* rp = red + (size_t)ksub * 2048 + (size_t)cg * 4 * 64 + mq * 4;
#pragma unroll
    for (int c = 0; c < 4; ++c)
      *(float4*)(rp + (size_t)c * 64) =
          make_float4(acc[c * 4], acc[c * 4 + 1], acc[c * 4 + 2], acc[c * 4 + 3]);
  }
  __syncthreads();
  {
    __half* pbase = part16 + ((size_t)s * 1024 + c0) * 64;   // 2048 contiguous
#pragma unroll
    for (int ps5 = 0; ps5 < 2; ++ps5) {
      int idx = ps5 * 1024 + tid * 2;
      float2 a0 = *(const float2*)(red + idx);
      float2 a1 = *(const float2*)(red + 2048 + idx);
      float2 a2 = *(const float2*)(red + 4096 + idx);
      float2 a3 = *(const float2*)(red + 6144 + idx);
      float v0 = (a0.x + a1.x) + (a2.x + a3.x);
      float v1 = (a0.y + a1.y) + (a2.y + a3.y);
      ast32((unsigned*)(pbase + idx), pack2h(v0, v1));
    }
  }
}

__device__ __forceinline__ void p6b(const __half* __restrict__ part16,
                                    const float* __restrict__ b2,
                                    float* __restrict__ gin) {
  const int tid = threadIdx.x, bid = blockIdx.x;
  if (tid >= 256) return;
  const int c = bid * 4 + (tid >> 6), m = tid & 63;
  float v = 0.f;
#pragma unroll
  for (int s = 0; s < 8; ++s) v += aldh(part16 + ((size_t)s * 1024 + c) * 64 + m);
  ast(gin + (size_t)c * 64 + m, fmaxf(v + b2[c], 0.f));
}

__global__ __launch_bounds__(512, 1) void persist(P p) {
  cg::grid_group grid = cg::this_grid();
  // 160 KB: pinned gru1 planeA [0,8192) planeB [8192,12288) | gru2 planeA
  // [12288,20480) planeB [20480,24576) | scratch [24576,40960) = 64 KB.
  __shared__ float sm[40960];
  float* const SCR = sm + 24576;
  unsigned ep = 0;

  // ---- prologue (4 slow cg syncs flush prologue's normal stores) ----
  if (blockIdx.x == 0) {
    for (int i = threadIdx.x; i < 1024; i += 512) p.bar[i] = 0u;
  }
  if (threadIdx.x < 64) {  // z transpose -> h1 region (consumed pre-overwrite)
    int i = blockIdx.x * 64 + threadIdx.x;
    int m = i >> 8, l = i & 255;
    p.h1[l * 64 + m] = p.z[i];
  }
  matmat<1024, 1024, 8>(p.Wv, p.Wo, p.part);            // Wvo (fp32 temp)
  vecmat(p.bh, p.w1, p.b1, p.bhw1, 256, 1024, 0, 2);
  vecmat(p.bv, p.Wo, p.bo, p.bvo, 1024, 1024, 2, 2);
  cvt_copy(p.Whh0, p.Whh0h, 786432);                    // raw weights -> fp16
  cvt_copy(p.Wih1, p.Wih1h, 786432);
  cvt_copy(p.Whh1, p.Whh1h, 786432);
  cvt_copy(p.w2,   p.w2h,   262144);
  cvt_copy(p.Wh,   p.Whh,   65536);
  grid.sync();
  matmat<1024, 3072, 24>(p.part, p.Wih0, p.Wvoihh);     // Wvoih -> fp16 direct
  matmat<256, 1024, 8>(p.Wh, p.w1, p.WhW1h);            // WhW1 -> fp16 direct
  vecmat(p.bvo, p.Wih0, p.bih0, p.bfold, 1024, 3072, 0, 6);
  grid.sync();
  gemv1024(p.h1, p.w1, p.b1, 256, 1, p.t1, nullptr, nullptr, SCR);
  grid.sync();
  gemv1024(p.t1, p.w2, p.b2, 1024, 0, p.h1, p.h2, p.gin, SCR);
  grid.sync();

  // ---- pin gru weight tiles once (reused for all 128 steps) ----
  const int s0 = blockIdx.x & 7, g0 = blockIdx.x >> 3;
  const int c00 = g0 * 96, k00 = (s0 & 3) * 256;
  pin_w((s0 < 4 ? p.Wvoihh : p.Whh0h), k00, c00, sm, sm + 8192);
  pin_w((s0 < 4 ? p.Wih1h  : p.Whh1h), k00, c00, sm + 12288, sm + 20480);
  __syncthreads();

  // ---- time loop: 8 fence-free phases/step ----
  for (int t = 0; t < TSTEP; ++t) {
    gru_mm_p((s0 < 4 ? p.gin : p.h1) + (size_t)k00 * 64, (const __half*)sm,
             (const __half*)(sm + 8192), s0, c00, p.part16, SCR);
    fastbar(p.bar, ep);
    gru_comb(p.part16, p.bfold, p.bhh0, p.h1);            fastbar(p.bar, ep);
    gru_mm_p((s0 < 4 ? p.h1 : p.h2) + (size_t)k00 * 64, (const __half*)(sm + 12288),
             (const __half*)(sm + 20480), s0, c00, p.part16, SCR);
    fastbar(p.bar, ep);
    gru_comb(p.part16, p.bih1, p.bhh1, p.h2);             fastbar(p.bar, ep);
    p5_mm(p.WhW1h, p.Whh, p.h2, p.part16, SCR);           fastbar(p.bar, ep);
    p5b(p.part16, p.bhw1, p.bh, p.t1, p.out, t);          fastbar(p.bar, ep);
    p6_mm(p.w2h, p.t1, p.part16, SCR);                    fastbar(p.bar, ep);
    p6b(p.part16, p.b2, p.gin);                           fastbar(p.bar, ep);
  }
}

// ---------------------------------------------------------------------------
// Fallback path (round-2 verified multi-kernel, fp32 — unchanged).
// ---------------------------------------------------------------------------
__global__ void fb_transpose(const float* __restrict__ z, float* __restrict__ zT) {
  int i = blockIdx.x * 256 + threadIdx.x;
  int m = i >> 8, l = i & 255;
  zT[l * 64 + m] = z[i];
}
__global__ void fb_copy2(const float* __restrict__ s, float* __restrict__ d1,
                         float* __restrict__ d2) {
  int i = blockIdx.x * 256 + threadIdx.x;
  float v = s[i]; d1[i] = v; d2[i] = v;
}
template <int ACT>
__global__ void fb_gemm(const float* __restrict__ A_T, const float* __restrict__ W,
                        const float* __restrict__ bias, float* __restrict__ C_T,
                        int K, int N, float* __restrict__ outp, int tstep) {
  const int m = threadIdx.x & 63;
  const int wv = threadIdx.x >> 6;
  const int c = blockIdx.x * 4 + wv;
  float acc0 = 0.f, acc1 = 0.f;
  const float* ap = A_T + m;
  const float* wp = W + c;
#pragma unroll 4
  for (int k = 0; k + 1 < K; k += 2) {
    acc0 = fmaf(ap[k * 64], wp[(size_t)k * N], acc0);
    acc1 = fmaf(ap[(k + 1) * 64], wp[(size_t)(k + 1) * N], acc1);
  }
  float v0 = acc0 + acc1 + bias[c];
  if (ACT) v0 = fmaxf(v0, 0.f);
  C_T[c * 64 + m] = v0;
  if (outp != nullptr) outp[(size_t)(m * TSTEP + tstep) * LATD + c] = v0;
}
__global__ void fb_gru(const float* __restrict__ xT, const float* __restrict__ hT,
                       const float* __restrict__ Wih, const float* __restrict__ Whh,
                       const float* __restrict__ bih, const float* __restrict__ bhh,
                       float* __restrict__ hnT) {
  const int m = threadIdx.x & 63;
  const int wv = threadIdx.x >> 6;
  const int c = blockIdx.x * 4 + wv;
  float racc = 0, zacc = 0, iacc = 0, nacc = 0;
  const float* xp = xT + m;
  const float* hp = hT + m;
  const float* wi = Wih + c;
  const float* wh = Whh + c;
#pragma unroll 2
  for (int k = 0; k < 1024; ++k) {
    float a = xp[k * 64];
    float h = hp[k * 64];
    const float* wik = wi + (size_t)k * 3072;
    const float* whk = wh + (size_t)k * 3072;
    racc = fmaf(a, wik[0], racc); racc = fmaf(h, whk[0], racc);
    zacc = fmaf(a, wik[1024], zacc); zacc = fmaf(h, whk[1024], zacc);
    iacc = fmaf(a, wik[2048], iacc);
    nacc = fmaf(h, whk[2048], nacc);
  }
  float r = 1.f / (1.f + expf(-(racc + bih[c] + bhh[c])));
  float zg = 1.f / (1.f + expf(-(zacc + bih[1024 + c] + bhh[1024 + c])));
  float nn = tanhf(iacc + bih[2048 + c] + r * (nacc + bhh[2048 + c]));
  hnT[c * 64 + m] = (1.f - zg) * nn + zg * hT[c * 64 + m];
}

extern "C" void kernel_launch(void* const* d_in, const int* in_sizes, int n_in,
                              void* d_out, int out_size, void* d_ws, size_t ws_size,
                              hipStream_t stream) {
  const float* z_start = (const float*)d_in[0];
  const float* w1 = (const float*)d_in[2];
  const float* b1 = (const float*)d_in[3];
  const float* w2 = (const float*)d_in[4];
  const float* b2 = (const float*)d_in[5];
  const float* Wv = (const float*)d_in[10];
  const float* bv = (const float*)d_in[11];
  const float* Wo = (const float*)d_in[12];
  const float* bo = (const float*)d_in[13];
  const float* Wih0 = (const float*)d_in[14];
  const float* Whh0 = (const float*)d_in[15];
  const float* bih0 = (const float*)d_in[16];
  const float* bhh0 = (const float*)d_in[17];
  const float* Wih1 = (const float*)d_in[18];
  const float* Whh1 = (const float*)d_in[19];
  const float* bih1 = (const float*)d_in[20];
  const float* bhh1 = (const float*)d_in[21];
  const float* Wh = (const float*)d_in[22];
  const float* bh = (const float*)d_in[23];
  float* out = (float*)d_out;
  float* ws = (float*)d_ws;

  // floats: 4x1572864 (fp16 wbufs) + part 1572864 (Wvo fp32 temp in
  // prologue; 8x3072x64 fp16 partials in loop) + 524288x2 (WhW1_h,w2_h) +
  // 131072 (Wh_h) + 4x65536 acts + 5120 small + 1024 bar
  const size_t need = (size_t)9312256 * 4;
  if (ws_size >= need) {
    P p;
    p.z = z_start; p.w1 = w1; p.b1 = b1; p.w2 = w2; p.b2 = b2;
    p.Wv = Wv; p.bv = bv; p.Wo = Wo; p.bo = bo;
    p.Wih0 = Wih0; p.Whh0 = Whh0; p.bih0 = bih0; p.bhh0 = bhh0;
    p.Wih1 = Wih1; p.Whh1 = Whh1; p.bih1 = bih1; p.bhh1 = bhh1;
    p.Wh = Wh; p.bh = bh; p.out = out;
    float* q = ws;
    p.Wvoihh = (__half*)q; q += 1572864;   // 1024x3072 halves
    p.Whh0h  = (__half*)q; q += 1572864;
    p.Wih1h  = (__half*)q; q += 1572864;
    p.Whh1h  = (__half*)q; q += 1572864;
    p.WhW1h  = (__half*)q; q += 524288;    // 1024x1024 halves
    p.Whh    = (__half*)q; q += 131072;    // 1024x256 halves
    p.w2h    = (__half*)q; q += 524288;
    p.part = q; q += 1572864;   // Wvo fp32 temp in prologue; fp16 parts loop
    p.part16 = (__half*)p.part;
    p.gin = q; q += 65536;
    p.h1 = q; q += 65536;       // also zT during prologue
    p.h2 = q; q += 65536;
    p.t1 = q; q += 65536;
    p.bvo = q; q += 1024;
    p.bfold = q; q += 3072;
    p.bhw1 = q; q += 1024;
    p.bar = (unsigned*)q; q += 1024;
    void* args[] = { &p };
    hipError_t e = hipLaunchCooperativeKernel((const void*)persist, dim3(256),
                                              dim3(512), args, 0, stream);
    if (e == hipSuccess) return;
  }

  // -------- fallback: verified round-2 path --------
  float* zsT = ws;
  float* vT = zsT + 16384;
  float* xaT = vT + 65536;
  float* t1T = xaT + 65536;
  float* ginT = t1T + 65536;
  float* nzT = ginT + 65536;
  float* h1T = nzT + 16384;
  float* h2T = h1T + 2 * 65536;

  fb_transpose<<<64, 256, 0, stream>>>(z_start, zsT);
  fb_gemm<1><<<256, 256, 0, stream>>>(zsT, w1, b1, t1T, 256, 1024, nullptr, 0);
  fb_gemm<0><<<256, 256, 0, stream>>>(t1T, w2, b2, h1T, 1024, 1024, nullptr, 0);
  fb_copy2<<<256, 256, 0, stream>>>(h1T, h2T, ginT);
  for (int t = 0; t < TSTEP; ++t) {
    float* h1p = h1T + (t & 1) * 65536;
    float* h1n = h1T + ((t + 1) & 1) * 65536;
    float* h2p = h2T + (t & 1) * 65536;
    float* h2n = h2T + ((t + 1) & 1) * 65536;
    fb_gemm<0><<<256, 256, 0, stream>>>(ginT, Wv, bv, vT, 1024, 1024, nullptr, 0);
    fb_gemm<0><<<256, 256, 0, stream>>>(vT, Wo, bo, xaT, 1024, 1024, nullptr, 0);
    fb_gru<<<256, 256, 0, stream>>>(xaT, h1p, Wih0, Whh0, bih0, bhh0, h1n);
    fb_gru<<<256, 256, 0, stream>>>(h1n, h2p, Wih1, Whh1, bih1, bhh1, h2n);
    fb_gemm<0><<<64, 256, 0, stream>>>(h2n, Wh, bh, nzT, 1024, 256, out, t);
    fb_gemm<1><<<256, 256, 0, stream>>>(nzT, w1, b1, t1T, 256, 1024, nullptr, 0);
    fb_gemm<1><<<256, 256, 0, stream>>>(t1T, w2, b2, ginT, 1024, 1024, nullptr, 0);
  }
}

// Round 12
// 10947.816 us; speedup vs baseline: 1.1069x; 1.0650x over previous
//
#include <hip/hip_runtime.h>
#include <hip/hip_cooperative_groups.h>
#include <hip/hip_fp16.h>

namespace cg = cooperative_groups;

#define TSTEP 128
#define LATD 256

// ---------------------------------------------------------------------------
// R19 = R18 (verified 11.66 ms) + fp16 loop activations.
// R18 counters: conflicts fixed (6.4e7), FETCH 25.6 MB/step now dominated by
// fp32 act staging over the agent-scope (sc1) path; phases latency-bound.
// Fix: gin/h1/h2/t1 stored fp16 in the loop (aliased into the free back half
// of the part region -- no ws growth). Act staging bytes AND sc1 load count
// halve (gru 16->8 ald64/thread, p5/p6 8->4); combines write state as dense
// 2B stores; FMA cores add 4 v_cvt per k (cheap). Prologue: one act
// fp32->fp16 conversion pass + one extra grid.sync. Everything else --
// pinned gru weights, part-linear reduce, dense fp16 partial epilogue,
// barrier, phases -- verbatim R18.
// Precision: recurrent fp16 h quantization ~1e-3*|h| (z~0.5 mixing);
// predicted absmax 1.5-2.5e-3 < 4.18e-3 threshold.
// Folds (verified R3-R18): Wvoih=(Wv@Wo)@Wih0, bfold=(bv@Wo+bo)@Wih0+bih0,
// WhW1=Wh@w1, bhw1=bh@w1+b1. Step = 8 phases.
// ---------------------------------------------------------------------------

typedef __attribute__((ext_vector_type(2))) unsigned long long u64x2;

struct P {
  const float *z, *w1, *b1, *w2, *b2, *Wv, *bv, *Wo, *bo;
  const float *Wih0, *Whh0, *bih0, *bhh0, *Wih1, *Whh1, *bih1, *bhh1, *Wh, *bh;
  float *out;
  __half *Wvoihh, *Whh0h, *Wih1h, *Whh1h, *WhW1h, *Whh, *w2h;
  float *part, *gin, *h1, *h2, *t1, *bvo, *bfold, *bhw1;
  __half *part16;                      // alias: part[0..786432) floats
  __half *gin16, *h116, *h216, *t116;  // alias: part[786432..917504) floats
  unsigned *bar;   // leaves at i*32 (i<16), root at 512, flag at 544
};

__device__ __forceinline__ float ald(const float* p) {
  return __hip_atomic_load((float*)p, __ATOMIC_RELAXED, __HIP_MEMORY_SCOPE_AGENT);
}
__device__ __forceinline__ void ast(float* p, float v) {
  __hip_atomic_store(p, v, __ATOMIC_RELAXED, __HIP_MEMORY_SCOPE_AGENT);
}
__device__ __forceinline__ void ast32(unsigned* p, unsigned v) {
  __hip_atomic_store(p, v, __ATOMIC_RELAXED, __HIP_MEMORY_SCOPE_AGENT);
}
__device__ __forceinline__ unsigned long long ald64(const unsigned long long* p) {
  return __hip_atomic_load((unsigned long long*)p, __ATOMIC_RELAXED,
                           __HIP_MEMORY_SCOPE_AGENT);
}
__device__ __forceinline__ float aldh(const __half* p) {
  unsigned short v = __hip_atomic_load((unsigned short*)p, __ATOMIC_RELAXED,
                                       __HIP_MEMORY_SCOPE_AGENT);
  __half h; *(unsigned short*)&h = v;
  return __half2float(h);
}
__device__ __forceinline__ void asth(__half* p, float v) {
  __half h = __float2half(v);
  __hip_atomic_store((unsigned short*)p, *(unsigned short*)&h, __ATOMIC_RELAXED,
                     __HIP_MEMORY_SCOPE_AGENT);
}
__device__ __forceinline__ unsigned pack2h(float x, float y) {
  union { unsigned u; __half h[2]; } c;
  c.h[0] = __float2half(x); c.h[1] = __float2half(y);
  return c.u;
}
__device__ __forceinline__ float4 h4f(unsigned long long u) {
  union { unsigned long long q; __half h[4]; } c; c.q = u;
  return make_float4(__half2float(c.h[0]), __half2float(c.h[1]),
                     __half2float(c.h[2]), __half2float(c.h[3]));
}
__device__ __forceinline__ unsigned long long f4h4(float4 v) {
  union { unsigned long long q; __half h[4]; } c;
  c.h[0] = __float2half(v.x); c.h[1] = __float2half(v.y);
  c.h[2] = __float2half(v.z); c.h[3] = __float2half(v.w);
  return c.q;
}

// Fence-free hierarchical grid barrier (R7-proven; R12 version).
__device__ __forceinline__ void fastbar(unsigned* bar, unsigned& ep) {
  ++ep;
  __atomic_signal_fence(__ATOMIC_SEQ_CST);
  __builtin_amdgcn_s_waitcnt(0);
  __atomic_signal_fence(__ATOMIC_SEQ_CST);
  __syncthreads();
  if (threadIdx.x == 0) {
    unsigned* leaf = bar + (blockIdx.x & 15u) * 32u;
    unsigned a = atomicAdd(leaf, 1u);
    if (a == ep * 16u - 1u) {
      unsigned r = atomicAdd(bar + 512, 1u);
      if (r == ep * 16u - 1u)
        __hip_atomic_store(bar + 544, ep, __ATOMIC_RELAXED, __HIP_MEMORY_SCOPE_AGENT);
    }
    while (__hip_atomic_load(bar + 544, __ATOMIC_RELAXED, __HIP_MEMORY_SCOPE_AGENT) < ep)
      __builtin_amdgcn_s_sleep(1);
  }
  __syncthreads();
}

// ---- prologue helpers (256 blocks x 512 threads; identical to R18) --------
__device__ __forceinline__ void stv(float* p, float v) { *p = v; }
__device__ __forceinline__ void stv(__half* p, float v) { *p = __float2half(v); }

template <int J, int N, int CPT, typename OT>
__device__ void matmat(const float* __restrict__ A, const float* __restrict__ B,
                       OT* __restrict__ C) {
  const int tid = threadIdx.x;
  const int r = blockIdx.x * 4 + (tid >> 7);
  const int c0 = tid & 127;
  float acc[CPT];
#pragma unroll
  for (int i = 0; i < CPT; ++i) acc[i] = 0.f;
  const float* ar = A + (size_t)r * J;
#pragma unroll 2
  for (int j = 0; j < J; ++j) {
    float av = ar[j];
    const float* br = B + (size_t)j * N + c0;
#pragma unroll
    for (int i = 0; i < CPT; ++i) acc[i] = fmaf(av, br[i * 128], acc[i]);
  }
  OT* cr = C + (size_t)r * N + c0;
#pragma unroll
  for (int i = 0; i < CPT; ++i) stv(cr + (size_t)i * 128, acc[i]);
}

__device__ void cvt_copy(const float* __restrict__ s, __half* __restrict__ d,
                         int n4) {
  for (int i = (int)(blockIdx.x * 512u + threadIdx.x); i < n4; i += 131072)
    *(unsigned long long*)(d + (size_t)i * 4) = f4h4(*(const float4*)(s + (size_t)i * 4));
}

__device__ void vecmat(const float* __restrict__ v, const float* __restrict__ M,
                       const float* __restrict__ badd, float* __restrict__ outv,
                       int J, int N, int blk0, int nblk) {
  int b = (int)blockIdx.x;
  if (b < blk0 || b >= blk0 + nblk) return;
  int gid = (b - blk0) * 512 + threadIdx.x;
  if (gid >= N) return;
  float acc = 0.f;
#pragma unroll 4
  for (int j = 0; j < J; ++j) acc = fmaf(v[j], M[(size_t)j * N + gid], acc);
  outv[gid] = acc + badd[gid];
}

__device__ void gemv1024(const float* __restrict__ A, const float* __restrict__ W,
                         const float* __restrict__ bias, int K, int relu,
                         float* __restrict__ C, float* __restrict__ C2,
                         float* __restrict__ C3, float* red) {
  const int tid = threadIdx.x;
  const int m = tid & 63, w = tid >> 6;
  const int j = w & 3, hh = w >> 2;
  const int c = blockIdx.x * 4 + j;
  const int kh = K >> 1;
  const float* a = A + m + (hh * kh) * 64;
  const float* wp = W + c + (size_t)(hh * kh) * 1024;
  float acc = 0.f;
#pragma unroll 8
  for (int k = 0; k < kh; ++k) acc = fmaf(a[k * 64], wp[(size_t)k * 1024], acc);
  if (hh) red[j * 64 + m] = acc;
  __syncthreads();
  if (!hh) {
    float v = acc + red[j * 64 + m] + bias[c];
    if (relu) v = fmaxf(v, 0.f);
    C[c * 64 + m] = v;
    if (C2) C2[c * 64 + m] = v;
    if (C3) C3[c * 64 + m] = v;
  }
  __syncthreads();
}

// ---- pin one gru weight tile (256 rows x 96 cols fp16) into LDS planes ----
__device__ void pin_w(const __half* __restrict__ W, int k0, int c0,
                      float* __restrict__ paf, float* __restrict__ pbf) {
  const int tid = threadIdx.x;
  const int k = tid >> 1, hr = tid & 1;
  const unsigned long long* Wr =
      (const unsigned long long*)(W + (size_t)(k0 + k) * 3072 + c0) + hr * 12;
  unsigned long long* pa = (unsigned long long*)paf + k * 16 + hr * 8;
  unsigned long long* pb = (unsigned long long*)pbf + k * 8 + hr * 4;
#pragma unroll
  for (int j = 0; j < 4; ++j) {
    unsigned long long q0 = Wr[j * 3];
    unsigned long long q1 = Wr[j * 3 + 1];
    unsigned long long q2 = Wr[j * 3 + 2];
    pa[j * 2] = q0; pa[j * 2 + 1] = q1; pb[j] = q2;
  }
}

// ---- GRU matmul (pinned weights, fp16 acts) -------------------------------
// Acts fp16: stage 4096 u64 (8/thread); LDS act [256][64]h = 8192 f.
// Per k: 1 b64 act (+4 cvt) + 1 b128 wA + 1 b64 wB / 48 FMA.
// Reduce: part-linear regions A/B @scr (6144 f each), 2+merge, dense fp16
// epilogue (verbatim R18).
__device__ __forceinline__ void gru_mm_p(const __half* __restrict__ A16,
                                         const __half* __restrict__ planeA,
                                         const __half* __restrict__ planeB,
                                         int s, int c0,
                                         __half* __restrict__ part16,
                                         float* __restrict__ scr) {
  const int tid = threadIdx.x;
  {  // stage acts (4096 u64)
    const unsigned long long* Ab = (const unsigned long long*)A16;
    unsigned long long* Sb = (unsigned long long*)scr;
#pragma unroll
    for (int i = 0; i < 8; ++i) Sb[tid + i * 512] = ald64(Ab + tid + i * 512);
  }
  __syncthreads();

  const int ksub = tid >> 7, u = tid & 127;
  const int mq = u & 15, cg = u >> 4;
  float acc[48];
#pragma unroll
  for (int j = 0; j < 48; ++j) acc[j] = 0.f;
  const __half* ap = (const __half*)scr + (size_t)(ksub * 64) * 64 + mq * 4;
  const __half* wa = planeA + (size_t)(ksub * 64) * 64 + cg * 8;
  const __half* wb = planeB + (size_t)(ksub * 64) * 32 + cg * 4;
#pragma unroll 2
  for (int k = 0; k < 64; ++k) {
    float4 a4 = h4f(*(const unsigned long long*)(ap + k * 64));
    union { u64x2 v; __half h[8]; } ua;
    ua.v = *(const u64x2*)(wa + k * 64);
    union { unsigned long long v; __half h[4]; } ub;
    ub.v = *(const unsigned long long*)(wb + k * 32);
#pragma unroll
    for (int c = 0; c < 8; ++c) {
      float wf = __half2float(ua.h[c]);
      acc[c * 4 + 0] = fmaf(a4.x, wf, acc[c * 4 + 0]);
      acc[c * 4 + 1] = fmaf(a4.y, wf, acc[c * 4 + 1]);
      acc[c * 4 + 2] = fmaf(a4.z, wf, acc[c * 4 + 2]);
      acc[c * 4 + 3] = fmaf(a4.w, wf, acc[c * 4 + 3]);
    }
#pragma unroll
    for (int c = 0; c < 4; ++c) {
      float wf = __half2float(ub.h[c]);
      acc[32 + c * 4 + 0] = fmaf(a4.x, wf, acc[32 + c * 4 + 0]);
      acc[32 + c * 4 + 1] = fmaf(a4.y, wf, acc[32 + c * 4 + 1]);
      acc[32 + c * 4 + 2] = fmaf(a4.z, wf, acc[32 + c * 4 + 2]);
      acc[32 + c * 4 + 3] = fmaf(a4.w, wf, acc[32 + c * 4 + 3]);
    }
  }
  // ---- reduce: part-linear regions, 2+merge, dense epilogue (R18) ----
  __syncthreads();            // acts dead
  float* regA = scr;          // [6144] col_local*64 + m
  float* regB = scr + 6144;   // [6144]
  auto wrPL = [&](float* r0) {
    float* rp = r0 + (size_t)cg * 12 * 64 + mq * 4;
#pragma unroll
    for (int c = 0; c < 8; ++c)
      *(float4*)(rp + (size_t)c * 64) =
          make_float4(acc[c * 4], acc[c * 4 + 1], acc[c * 4 + 2], acc[c * 4 + 3]);
#pragma unroll
    for (int c = 0; c < 4; ++c)
      *(float4*)(rp + (size_t)(8 + c) * 64) =
          make_float4(acc[32 + c * 4], acc[32 + c * 4 + 1],
                      acc[32 + c * 4 + 2], acc[32 + c * 4 + 3]);
  };
  auto addPL = [&](const float* r0) {
    const float* rp = r0 + (size_t)cg * 12 * 64 + mq * 4;
#pragma unroll
    for (int c = 0; c < 8; ++c) {
      float4 r4 = *(const float4*)(rp + (size_t)c * 64);
      acc[c * 4] += r4.x; acc[c * 4 + 1] += r4.y;
      acc[c * 4 + 2] += r4.z; acc[c * 4 + 3] += r4.w;
    }
#pragma unroll
    for (int c = 0; c < 4; ++c) {
      float4 r4 = *(const float4*)(rp + (size_t)(8 + c) * 64);
      acc[32 + c * 4] += r4.x; acc[32 + c * 4 + 1] += r4.y;
      acc[32 + c * 4 + 2] += r4.z; acc[32 + c * 4 + 3] += r4.w;
    }
  };
  if (ksub == 1) wrPL(regA);
  if (ksub == 3) wrPL(regB);
  __syncthreads();
  if (ksub == 0) { addPL(regA); wrPL(regA); }
  if (ksub == 2) { addPL(regB); wrPL(regB); }
  __syncthreads();
  {
    __half* pbase = part16 + ((size_t)s * 3072 + c0) * 64;   // 6144 contiguous
#pragma unroll
    for (int ps5 = 0; ps5 < 6; ++ps5) {
      int idx = ps5 * 1024 + tid * 2;
      float2 a0 = *(const float2*)(regA + idx);
      float2 b0 = *(const float2*)(regB + idx);
      ast32((unsigned*)(pbase + idx), pack2h(a0.x + b0.x, a0.y + b0.y));
    }
  }
}

// GRU combine: fp16 partials in, fp16 h state out. 256 blocks, 256 thr.
__device__ __forceinline__ void gru_comb(const __half* __restrict__ part16,
                                         const float* __restrict__ bx,
                                         const float* __restrict__ bm,
                                         __half* __restrict__ h16) {
  const int tid = threadIdx.x, bid = blockIdx.x;
  if (tid >= 256) return;
  const int c = bid * 4 + (tid >> 6), m = tid & 63;
  float ra = 0.f, za = 0.f, ia = 0.f, na = 0.f;
#pragma unroll
  for (int s = 0; s < 8; ++s) {
    const __half* ps = part16 + (size_t)s * 3072 * 64;
    ra += aldh(ps + (size_t)c * 64 + m);
    za += aldh(ps + (size_t)(1024 + c) * 64 + m);
    float nv = aldh(ps + (size_t)(2048 + c) * 64 + m);
    if (s < 4) ia += nv; else na += nv;
  }
  float r  = 1.f / (1.f + expf(-(ra + bx[c] + bm[c])));
  float zg = 1.f / (1.f + expf(-(za + bx[1024 + c] + bm[1024 + c])));
  float nn = tanhf(ia + bx[2048 + c] + r * (na + bm[2048 + c]));
  float hp = aldh(h16 + (size_t)c * 64 + m);
  asth(h16 + (size_t)c * 64 + m, (1.f - zg) * nn + zg * hp);
}

// ---- P5 (fp16 acts): C=1280, 32 groups(40) x 8 K-slices(128) --------------
__device__ __forceinline__ void p5_mm(const __half* __restrict__ WhW1,
                                      const __half* __restrict__ Whd,
                                      const __half* __restrict__ h216,
                                      __half* __restrict__ part16,
                                      float* __restrict__ sm) {
  const int tid = threadIdx.x, bid = blockIdx.x;
  const int g = bid >> 3, s = bid & 7;
  const int c0 = g * 40;
  const int k0 = s * 128;

  {  // stage acts (2048 u64)
    const unsigned long long* Ab =
        (const unsigned long long*)(h216 + (size_t)k0 * 64);
    unsigned long long* Sb = (unsigned long long*)sm;
#pragma unroll
    for (int i = 0; i < 4; ++i) Sb[tid + i * 512] = ald64(Ab + tid + i * 512);
  }
  {  // stage weights: 1024 (row,grp) pairs, 5 scalar halves each, padded 8
    __half* Sw = (__half*)(sm + 8192);
#pragma unroll
    for (int r = 0; r < 2; ++r) {
      int i2 = tid + r * 512;
      int row = i2 & 127, grp = i2 >> 7;
      const int gcb = c0 + grp * 5;
      __half* dst = Sw + row * 64 + grp * 8;
#pragma unroll
      for (int j = 0; j < 5; ++j) {
        int gc = gcb + j;
        dst[j] = (gc < 1024) ? WhW1[(size_t)(k0 + row) * 1024 + gc]
                             : Whd[(size_t)(k0 + row) * 256 + (gc - 1024)];
      }
    }
  }
  __syncthreads();

  const int ksub = tid >> 7, u = tid & 127;
  const int mq = u & 15, cg = u >> 4;
  float acc[20];
#pragma unroll
  for (int j = 0; j < 20; ++j) acc[j] = 0.f;
  const __half* ap = (const __half*)sm + (size_t)(ksub * 32) * 64 + mq * 4;
  const __half* wp = (const __half*)(sm + 8192) + (size_t)(ksub * 32) * 64 + cg * 8;
#pragma unroll 4
  for (int k = 0; k < 32; ++k) {
    float4 a4 = h4f(*(const unsigned long long*)(ap + k * 64));
    union { u64x2 v; __half h[8]; } uw;
    uw.v = *(const u64x2*)(wp + k * 64);
#pragma unroll
    for (int cc = 0; cc < 5; ++cc) {
      float wf = __half2float(uw.h[cc]);
      acc[cc * 4 + 0] = fmaf(a4.x, wf, acc[cc * 4 + 0]);
      acc[cc * 4 + 1] = fmaf(a4.y, wf, acc[cc * 4 + 1]);
      acc[cc * 4 + 2] = fmaf(a4.z, wf, acc[cc * 4 + 2]);
      acc[cc * 4 + 3] = fmaf(a4.w, wf, acc[cc * 4 + 3]);
    }
  }
  __syncthreads();
  float* red = sm;   // 4 regions x 2560 floats, layout = col_local*64 + m
  {
    float* rp = red + (size_t)ksub * 2560 + (size_t)cg * 5 * 64 + mq * 4;
#pragma unroll
    for (int cc = 0; cc < 5; ++cc)
      *(float4*)(rp + (size_t)cc * 64) =
          make_float4(acc[cc * 4], acc[cc * 4 + 1], acc[cc * 4 + 2], acc[cc * 4 + 3]);
  }
  __syncthreads();
  {
    __half* pbase = part16 + ((size_t)s * 1280 + c0) * 64;   // 2560 contiguous
#pragma unroll
    for (int ps5 = 0; ps5 < 3; ++ps5) {
      int idx = ps5 * 1024 + tid * 2;
      if (idx < 2560) {
        float2 a0 = *(const float2*)(red + idx);
        float2 a1 = *(const float2*)(red + 2560 + idx);
        float2 a2 = *(const float2*)(red + 5120 + idx);
        float2 a3 = *(const float2*)(red + 7680 + idx);
        float v0 = (a0.x + a1.x) + (a2.x + a3.x);
        float v1 = (a0.y + a1.y) + (a2.y + a3.y);
        ast32((unsigned*)(pbase + idx), pack2h(v0, v1));
      }
    }
  }
}

// P5 combine: t1 (fp16) cols 0..1023 (tid<256), out cols 1024..1279.
__device__ __forceinline__ void p5b(const __half* __restrict__ part16,
                                    const float* __restrict__ bhw1,
                                    const float* __restrict__ bh,
                                    __half* __restrict__ t116,
                                    float* __restrict__ out, int t) {
  const int tid = threadIdx.x, bid = blockIdx.x;
  if (tid < 256) {
    const int c = bid * 4 + (tid >> 6), m = tid & 63;
    float v = 0.f;
#pragma unroll
    for (int s = 0; s < 8; ++s) v += aldh(part16 + ((size_t)s * 1280 + c) * 64 + m);
    asth(t116 + (size_t)c * 64 + m, fmaxf(v + bhw1[c], 0.f));
  } else if (tid < 320) {
    const int m = tid - 256, c2 = bid;
    float v = 0.f;
#pragma unroll
    for (int s = 0; s < 8; ++s)
      v += aldh(part16 + ((size_t)s * 1280 + 1024 + c2) * 64 + m);
    out[(size_t)(m * TSTEP + t) * LATD + c2] = v + bh[c2];
  }
}

// P6 (fp16 acts).
__device__ __forceinline__ void p6_mm(const __half* __restrict__ w2h,
                                      const __half* __restrict__ t116,
                                      __half* __restrict__ part16,
                                      float* __restrict__ sm) {
  const int tid = threadIdx.x;
  const int bid = blockIdx.x;
  const int g = bid >> 3, s = bid & 7;
  const int c0 = g * 32;
  const int k0 = s * 128;

  {  // stage acts (2048 u64)
    const unsigned long long* Ab =
        (const unsigned long long*)(t116 + (size_t)k0 * 64);
    unsigned long long* Sb = (unsigned long long*)sm;
#pragma unroll
    for (int i = 0; i < 4; ++i) Sb[tid + i * 512] = ald64(Ab + tid + i * 512);
  }
  {  // stage weights: 1024 8B-chunks (4 halves each)
    unsigned long long* Sw = (unsigned long long*)(sm + 8192);
#pragma unroll
    for (int i = 0; i < 2; ++i) {
      int q = tid + i * 512;
      int k = q >> 3, cq = q & 7;
      Sw[k * 8 + cq] =
          *(const unsigned long long*)(w2h + (size_t)(k0 + k) * 1024 + c0 + cq * 4);
    }
  }
  __syncthreads();

  const int ksub = tid >> 7, u = tid & 127;
  const int mq = u & 15, cg = u >> 4;
  float acc[16];
#pragma unroll
  for (int j = 0; j < 16; ++j) acc[j] = 0.f;
  const __half* ap = (const __half*)sm + (size_t)(ksub * 32) * 64 + mq * 4;
  const __half* wp = (const __half*)(sm + 8192) + (size_t)(ksub * 32) * 32 + cg * 4;
#pragma unroll 4
  for (int k = 0; k < 32; ++k) {
    float4 a4 = h4f(*(const unsigned long long*)(ap + k * 64));
    union { unsigned long long v; __half h[4]; } ub;
    ub.v = *(const unsigned long long*)(wp + k * 32);
#pragma unroll
    for (int c = 0; c < 4; ++c) {
      float wf = __half2float(ub.h[c]);
      acc[c * 4 + 0] = fmaf(a4.x, wf, acc[c * 4 + 0]);
      acc[c * 4 + 1] = fmaf(a4.y, wf, acc[c * 4 + 1]);
      acc[c * 4 + 2] = fmaf(a4.z, wf, acc[c * 4 + 2]);
      acc[c * 4 + 3] = fmaf(a4.w, wf, acc[c * 4 + 3]);
    }
  }
  __syncthreads();
  float* red = sm;   // 4 regions x 2048 floats
  {
    float* rp = red + (size_t)ksub * 2048 + (size_t)cg * 4 * 64 + mq * 4;
#pragma unroll
    for (int c = 0; c < 4; ++c)
      *(float4*)(rp + (size_t)c * 64) =
          make_float4(acc[c * 4], acc[c * 4 + 1], acc[c * 4 + 2], acc[c * 4 + 3]);
  }
  __syncthreads();
  {
    __half* pbase = part16 + ((size_t)s * 1024 + c0) * 64;   // 2048 contiguous
#pragma unroll
    for (int ps5 = 0; ps5 < 2; ++ps5) {
      int idx = ps5 * 1024 + tid * 2;
      float2 a0 = *(const float2*)(red + idx);
      float2 a1 = *(const float2*)(red + 2048 + idx);
      float2 a2 = *(const float2*)(red + 4096 + idx);
      float2 a3 = *(const float2*)(red + 6144 + idx);
      float v0 = (a0.x + a1.x) + (a2.x + a3.x);
      float v1 = (a0.y + a1.y) + (a2.y + a3.y);
      ast32((unsigned*)(pbase + idx), pack2h(v0, v1));
    }
  }
}

__device__ __forceinline__ void p6b(const __half* __restrict__ part16,
                                    const float* __restrict__ b2,
                                    __half* __restrict__ gin16) {
  const int tid = threadIdx.x, bid = blockIdx.x;
  if (tid >= 256) return;
  const int c = bid * 4 + (tid >> 6), m = tid & 63;
  float v = 0.f;
#pragma unroll
  for (int s = 0; s < 8; ++s) v += aldh(part16 + ((size_t)s * 1024 + c) * 64 + m);
  asth(gin16 + (size_t)c * 64 + m, fmaxf(v + b2[c], 0.f));
}

__global__ __launch_bounds__(512, 1) void persist(P p) {
  cg::grid_group grid = cg::this_grid();
  // 160 KB: pinned gru1 planeA [0,8192) planeB [8192,12288) | gru2 planeA
  // [12288,20480) planeB [20480,24576) | scratch [24576,40960) = 64 KB.
  __shared__ float sm[40960];
  float* const SCR = sm + 24576;
  unsigned ep = 0;

  // ---- prologue (5 slow cg syncs flush prologue's normal stores) ----
  if (blockIdx.x == 0) {
    for (int i = threadIdx.x; i < 1024; i += 512) p.bar[i] = 0u;
  }
  if (threadIdx.x < 64) {  // z transpose -> h1 region (consumed pre-overwrite)
    int i = blockIdx.x * 64 + threadIdx.x;
    int m = i >> 8, l = i & 255;
    p.h1[l * 64 + m] = p.z[i];
  }
  matmat<1024, 1024, 8>(p.Wv, p.Wo, p.part);            // Wvo (fp32 temp)
  vecmat(p.bh, p.w1, p.b1, p.bhw1, 256, 1024, 0, 2);
  vecmat(p.bv, p.Wo, p.bo, p.bvo, 1024, 1024, 2, 2);
  cvt_copy(p.Whh0, p.Whh0h, 786432);                    // raw weights -> fp16
  cvt_copy(p.Wih1, p.Wih1h, 786432);
  cvt_copy(p.Whh1, p.Whh1h, 786432);
  cvt_copy(p.w2,   p.w2h,   262144);
  cvt_copy(p.Wh,   p.Whh,   65536);
  grid.sync();
  matmat<1024, 3072, 24>(p.part, p.Wih0, p.Wvoihh);     // Wvoih -> fp16 direct
  matmat<256, 1024, 8>(p.Wh, p.w1, p.WhW1h);            // WhW1 -> fp16 direct
  vecmat(p.bvo, p.Wih0, p.bih0, p.bfold, 1024, 3072, 0, 6);
  grid.sync();
  gemv1024(p.h1, p.w1, p.b1, 256, 1, p.t1, nullptr, nullptr, SCR);
  grid.sync();
  gemv1024(p.t1, p.w2, p.b2, 1024, 0, p.h1, p.h2, p.gin, SCR);
  grid.sync();
  // convert initial states fp32 -> fp16 loop buffers (Wvo temp long dead)
  for (int i = (int)(blockIdx.x * 512u + threadIdx.x); i < 16384; i += 131072) {
    float4 v = *(const float4*)(p.h1 + (size_t)i * 4);
    unsigned long long q = f4h4(v);
    *(unsigned long long*)(p.h116 + (size_t)i * 4) = q;
    *(unsigned long long*)(p.h216 + (size_t)i * 4) = q;
    *(unsigned long long*)(p.gin16 + (size_t)i * 4) = q;
  }
  grid.sync();

  // ---- pin gru weight tiles once (reused for all 128 steps) ----
  const int s0 = blockIdx.x & 7, g0 = blockIdx.x >> 3;
  const int c00 = g0 * 96, k00 = (s0 & 3) * 256;
  pin_w((s0 < 4 ? p.Wvoihh : p.Whh0h), k00, c00, sm, sm + 8192);
  pin_w((s0 < 4 ? p.Wih1h  : p.Whh1h), k00, c00, sm + 12288, sm + 20480);
  __syncthreads();

  // ---- time loop: 8 fence-free phases/step ----
  for (int t = 0; t < TSTEP; ++t) {
    gru_mm_p((s0 < 4 ? p.gin16 : p.h116) + (size_t)k00 * 64, (const __half*)sm,
             (const __half*)(sm + 8192), s0, c00, p.part16, SCR);
    fastbar(p.bar, ep);
    gru_comb(p.part16, p.bfold, p.bhh0, p.h116);          fastbar(p.bar, ep);
    gru_mm_p((s0 < 4 ? p.h116 : p.h216) + (size_t)k00 * 64,
             (const __half*)(sm + 12288), (const __half*)(sm + 20480), s0, c00,
             p.part16, SCR);
    fastbar(p.bar, ep);
    gru_comb(p.part16, p.bih1, p.bhh1, p.h216);           fastbar(p.bar, ep);
    p5_mm(p.WhW1h, p.Whh, p.h216, p.part16, SCR);         fastbar(p.bar, ep);
    p5b(p.part16, p.bhw1, p.bh, p.t116, p.out, t);        fastbar(p.bar, ep);
    p6_mm(p.w2h, p.t116, p.part16, SCR);                  fastbar(p.bar, ep);
    p6b(p.part16, p.b2, p.gin16);                         fastbar(p.bar, ep);
  }
}

// ---------------------------------------------------------------------------
// Fallback path (round-2 verified multi-kernel, fp32 — unchanged).
// ---------------------------------------------------------------------------
__global__ void fb_transpose(const float* __restrict__ z, float* __restrict__ zT) {
  int i = blockIdx.x * 256 + threadIdx.x;
  int m = i >> 8, l = i & 255;
  zT[l * 64 + m] = z[i];
}
__global__ void fb_copy2(const float* __restrict__ s, float* __restrict__ d1,
                         float* __restrict__ d2) {
  int i = blockIdx.x * 256 + threadIdx.x;
  float v = s[i]; d1[i] = v; d2[i] = v;
}
template <int ACT>
__global__ void fb_gemm(const float* __restrict__ A_T, const float* __restrict__ W,
                        const float* __restrict__ bias, float* __restrict__ C_T,
                        int K, int N, float* __restrict__ outp, int tstep) {
  const int m = threadIdx.x & 63;
  const int wv = threadIdx.x >> 6;
  const int c = blockIdx.x * 4 + wv;
  float acc0 = 0.f, acc1 = 0.f;
  const float* ap = A_T + m;
  const float* wp = W + c;
#pragma unroll 4
  for (int k = 0; k + 1 < K; k += 2) {
    acc0 = fmaf(ap[k * 64], wp[(size_t)k * N], acc0);
    acc1 = fmaf(ap[(k + 1) * 64], wp[(size_t)(k + 1) * N], acc1);
  }
  float v0 = acc0 + acc1 + bias[c];
  if (ACT) v0 = fmaxf(v0, 0.f);
  C_T[c * 64 + m] = v0;
  if (outp != nullptr) outp[(size_t)(m * TSTEP + tstep) * LATD + c] = v0;
}
__global__ void fb_gru(const float* __restrict__ xT, const float* __restrict__ hT,
                       const float* __restrict__ Wih, const float* __restrict__ Whh,
                       const float* __restrict__ bih, const float* __restrict__ bhh,
                       float* __restrict__ hnT) {
  const int m = threadIdx.x & 63;
  const int wv = threadIdx.x >> 6;
  const int c = blockIdx.x * 4 + wv;
  float racc = 0, zacc = 0, iacc = 0, nacc = 0;
  const float* xp = xT + m;
  const float* hp = hT + m;
  const float* wi = Wih + c;
  const float* wh = Whh + c;
#pragma unroll 2
  for (int k = 0; k < 1024; ++k) {
    float a = xp[k * 64];
    float h = hp[k * 64];
    const float* wik = wi + (size_t)k * 3072;
    const float* whk = wh + (size_t)k * 3072;
    racc = fmaf(a, wik[0], racc); racc = fmaf(h, whk[0], racc);
    zacc = fmaf(a, wik[1024], zacc); zacc = fmaf(h, whk[1024], zacc);
    iacc = fmaf(a, wik[2048], iacc);
    nacc = fmaf(h, whk[2048], nacc);
  }
  float r = 1.f / (1.f + expf(-(racc + bih[c] + bhh[c])));
  float zg = 1.f / (1.f + expf(-(zacc + bih[1024 + c] + bhh[1024 + c])));
  float nn = tanhf(iacc + bih[2048 + c] + r * (nacc + bhh[2048 + c]));
  hnT[c * 64 + m] = (1.f - zg) * nn + zg * hT[c * 64 + m];
}

extern "C" void kernel_launch(void* const* d_in, const int* in_sizes, int n_in,
                              void* d_out, int out_size, void* d_ws, size_t ws_size,
                              hipStream_t stream) {
  const float* z_start = (const float*)d_in[0];
  const float* w1 = (const float*)d_in[2];
  const float* b1 = (const float*)d_in[3];
  const float* w2 = (const float*)d_in[4];
  const float* b2 = (const float*)d_in[5];
  const float* Wv = (const float*)d_in[10];
  const float* bv = (const float*)d_in[11];
  const float* Wo = (const float*)d_in[12];
  const float* bo = (const float*)d_in[13];
  const float* Wih0 = (const float*)d_in[14];
  const float* Whh0 = (const float*)d_in[15];
  const float* bih0 = (const float*)d_in[16];
  const float* bhh0 = (const float*)d_in[17];
  const float* Wih1 = (const float*)d_in[18];
  const float* Whh1 = (const float*)d_in[19];
  const float* bih1 = (const float*)d_in[20];
  const float* bhh1 = (const float*)d_in[21];
  const float* Wh = (const float*)d_in[22];
  const float* bh = (const float*)d_in[23];
  float* out = (float*)d_out;
  float* ws = (float*)d_ws;

  // floats: 4x1572864 (fp16 wbufs) + part 1572864 (Wvo fp32 temp in
  // prologue; loop: fp16 partials [0..786432)f + fp16 acts [786432..917504)f)
  // + 524288x2 (WhW1_h,w2_h) + 131072 (Wh_h) + 4x65536 fp32 acts (prologue)
  // + 5120 small + 1024 bar
  const size_t need = (size_t)9312256 * 4;
  if (ws_size >= need) {
    P p;
    p.z = z_start; p.w1 = w1; p.b1 = b1; p.w2 = w2; p.b2 = b2;
    p.Wv = Wv; p.bv = bv; p.Wo = Wo; p.bo = bo;
    p.Wih0 = Wih0; p.Whh0 = Whh0; p.bih0 = bih0; p.bhh0 = bhh0;
    p.Wih1 = Wih1; p.Whh1 = Whh1; p.bih1 = bih1; p.bhh1 = bhh1;
    p.Wh = Wh; p.bh = bh; p.out = out;
    float* q = ws;
    p.Wvoihh = (__half*)q; q += 1572864;   // 1024x3072 halves
    p.Whh0h  = (__half*)q; q += 1572864;
    p.Wih1h  = (__half*)q; q += 1572864;
    p.Whh1h  = (__half*)q; q += 1572864;
    p.WhW1h  = (__half*)q; q += 524288;    // 1024x1024 halves
    p.Whh    = (__half*)q; q += 131072;    // 1024x256 halves
    p.w2h    = (__half*)q; q += 524288;
    p.part = q; q += 1572864;   // Wvo fp32 temp / loop fp16 parts + acts
    p.part16 = (__half*)p.part;
    p.gin16 = (__half*)(p.part + 786432);
    p.h116  = (__half*)(p.part + 819200);
    p.h216  = (__half*)(p.part + 851968);
    p.t116  = (__half*)(p.part + 884736);
    p.gin = q; q += 65536;
    p.h1 = q; q += 65536;       // also zT during prologue
    p.h2 = q; q += 65536;
    p.t1 = q; q += 65536;
    p.bvo = q; q += 1024;
    p.bfold = q; q += 3072;
    p.bhw1 = q; q += 1024;
    p.bar = (unsigned*)q; q += 1024;
    void* args[] = { &p };
    hipError_t e = hipLaunchCooperativeKernel((const void*)persist, dim3(256),
                                              dim3(512), args, 0, stream);
    if (e == hipSuccess) return;
  }

  // -------- fallback: verified round-2 path --------
  float* zsT = ws;
  float* vT = zsT + 16384;
  float* xaT = vT + 65536;
  float* t1T = xaT + 65536;
  float* ginT = t1T + 65536;
  float* nzT = ginT + 65536;
  float* h1T = nzT + 16384;
  float* h2T = h1T + 2 * 65536;

  fb_transpose<<<64, 256, 0, stream>>>(z_start, zsT);
  fb_gemm<1><<<256, 256, 0, stream>>>(zsT, w1, b1, t1T, 256, 1024, nullptr, 0);
  fb_gemm<0><<<256, 256, 0, stream>>>(t1T, w2, b2, h1T, 1024, 1024, nullptr, 0);
  fb_copy2<<<256, 256, 0, stream>>>(h1T, h2T, ginT);
  for (int t = 0; t < TSTEP; ++t) {
    float* h1p = h1T + (t & 1) * 65536;
    float* h1n = h1T + ((t + 1) & 1) * 65536;
    float* h2p = h2T + (t & 1) * 65536;
    float* h2n = h2T + ((t + 1) & 1) * 65536;
    fb_gemm<0><<<256, 256, 0, stream>>>(ginT, Wv, bv, vT, 1024, 1024, nullptr, 0);
    fb_gemm<0><<<256, 256, 0, stream>>>(vT, Wo, bo, xaT, 1024, 1024, nullptr, 0);
    fb_gru<<<256, 256, 0, stream>>>(xaT, h1p, Wih0, Whh0, bih0, bhh0, h1n);
    fb_gru<<<256, 256, 0, stream>>>(h1n, h2p, Wih1, Whh1, bih1, bhh1, h2n);
    fb_gemm<0><<<64, 256, 0, stream>>>(h2n, Wh, bh, nzT, 1024, 256, out, t);
    fb_gemm<1><<<256, 256, 0, stream>>>(nzT, w1, b1, t1T, 256, 1024, nullptr, 0);
    fb_gemm<1><<<256, 256, 0, stream>>>(t1T, w2, b2, ginT, 1024, 1024, nullptr, 0);
  }
}

// Round 13
// 7893.199 us; speedup vs baseline: 1.5352x; 1.3870x over previous
//
#include <hip/hip_runtime.h>
#include <hip/hip_cooperative_groups.h>
#include <hip/hip_fp16.h>

namespace cg = cooperative_groups;

#define TSTEP 128
#define LATD 256

// ---------------------------------------------------------------------------
// R20 = R19 (verified 10.95 ms) + MFMA GRU phases.
// R19 counters: traffic solved (FETCH 6.5 MB/step, HBM 2.4%); remaining
// 85.5 us/step = ~25.6 us fp32-VALU FMA + 8x(barrier ~3.5 + stage ~2.5).
// The GRU mm phases are fp16 GEMMs (M=64,N=96/block,K=256/block) -> port to
// v_mfma_f32_16x16x32_f16: 8 waves x 3 tiles(16x16) x 8 mfma. No K-split
// across waves -> LDS reduce GONE. Acts staged transposed [m][k] and gru
// weights pinned transposed [c][k], both XOR-swizzled (byte ^= (row&7)<<4,
// G4) so b128 fragment reads are ~2-way. D layout (col=lane&15,
// row=(lane>>4)*4+reg) -> 4 consecutive m per lane -> one packed 8B fp16
// store into the UNCHANGED part16 layout. p5/p6 (25% of FLOPs, N=40/32)
// stay on the verified VALU path. Combines/barrier/prologue verbatim R19.
// Folds (verified R3-R19): Wvoih=(Wv@Wo)@Wih0, bfold=(bv@Wo+bo)@Wih0+bih0,
// WhW1=Wh@w1, bhw1=bh@w1+b1. Step = 8 phases.
// ---------------------------------------------------------------------------

typedef __attribute__((ext_vector_type(2))) unsigned long long u64x2;
typedef _Float16 f16x8_t __attribute__((ext_vector_type(8)));
typedef float f32x4_t __attribute__((ext_vector_type(4)));

struct P {
  const float *z, *w1, *b1, *w2, *b2, *Wv, *bv, *Wo, *bo;
  const float *Wih0, *Whh0, *bih0, *bhh0, *Wih1, *Whh1, *bih1, *bhh1, *Wh, *bh;
  float *out;
  __half *Wvoihh, *Whh0h, *Wih1h, *Whh1h, *WhW1h, *Whh, *w2h;
  float *part, *gin, *h1, *h2, *t1, *bvo, *bfold, *bhw1;
  __half *part16;                      // alias: part[0..786432) floats
  __half *gin16, *h116, *h216, *t116;  // alias: part[786432..917504) floats
  unsigned *bar;   // leaves at i*32 (i<16), root at 512, flag at 544
};

__device__ __forceinline__ float ald(const float* p) {
  return __hip_atomic_load((float*)p, __ATOMIC_RELAXED, __HIP_MEMORY_SCOPE_AGENT);
}
__device__ __forceinline__ void ast(float* p, float v) {
  __hip_atomic_store(p, v, __ATOMIC_RELAXED, __HIP_MEMORY_SCOPE_AGENT);
}
__device__ __forceinline__ void ast32(unsigned* p, unsigned v) {
  __hip_atomic_store(p, v, __ATOMIC_RELAXED, __HIP_MEMORY_SCOPE_AGENT);
}
__device__ __forceinline__ void ast64(unsigned long long* p, unsigned long long v) {
  __hip_atomic_store(p, v, __ATOMIC_RELAXED, __HIP_MEMORY_SCOPE_AGENT);
}
__device__ __forceinline__ unsigned long long ald64(const unsigned long long* p) {
  return __hip_atomic_load((unsigned long long*)p, __ATOMIC_RELAXED,
                           __HIP_MEMORY_SCOPE_AGENT);
}
__device__ __forceinline__ float aldh(const __half* p) {
  unsigned short v = __hip_atomic_load((unsigned short*)p, __ATOMIC_RELAXED,
                                       __HIP_MEMORY_SCOPE_AGENT);
  __half h; *(unsigned short*)&h = v;
  return __half2float(h);
}
__device__ __forceinline__ void asth(__half* p, float v) {
  __half h = __float2half(v);
  __hip_atomic_store((unsigned short*)p, *(unsigned short*)&h, __ATOMIC_RELAXED,
                     __HIP_MEMORY_SCOPE_AGENT);
}
__device__ __forceinline__ unsigned pack2h(float x, float y) {
  union { unsigned u; __half h[2]; } c;
  c.h[0] = __float2half(x); c.h[1] = __float2half(y);
  return c.u;
}
__device__ __forceinline__ unsigned long long pack4h(float a, float b, float c,
                                                     float d) {
  union { unsigned long long q; __half h[4]; } u;
  u.h[0] = __float2half(a); u.h[1] = __float2half(b);
  u.h[2] = __float2half(c); u.h[3] = __float2half(d);
  return u.q;
}
__device__ __forceinline__ float4 h4f(unsigned long long u) {
  union { unsigned long long q; __half h[4]; } c; c.q = u;
  return make_float4(__half2float(c.h[0]), __half2float(c.h[1]),
                     __half2float(c.h[2]), __half2float(c.h[3]));
}
__device__ __forceinline__ unsigned long long f4h4(float4 v) {
  union { unsigned long long q; __half h[4]; } c;
  c.h[0] = __float2half(v.x); c.h[1] = __float2half(v.y);
  c.h[2] = __float2half(v.z); c.h[3] = __float2half(v.w);
  return c.q;
}

// Fence-free hierarchical grid barrier (R7-proven; R12 version).
__device__ __forceinline__ void fastbar(unsigned* bar, unsigned& ep) {
  ++ep;
  __atomic_signal_fence(__ATOMIC_SEQ_CST);
  __builtin_amdgcn_s_waitcnt(0);
  __atomic_signal_fence(__ATOMIC_SEQ_CST);
  __syncthreads();
  if (threadIdx.x == 0) {
    unsigned* leaf = bar + (blockIdx.x & 15u) * 32u;
    unsigned a = atomicAdd(leaf, 1u);
    if (a == ep * 16u - 1u) {
      unsigned r = atomicAdd(bar + 512, 1u);
      if (r == ep * 16u - 1u)
        __hip_atomic_store(bar + 544, ep, __ATOMIC_RELAXED, __HIP_MEMORY_SCOPE_AGENT);
    }
    while (__hip_atomic_load(bar + 544, __ATOMIC_RELAXED, __HIP_MEMORY_SCOPE_AGENT) < ep)
      __builtin_amdgcn_s_sleep(1);
  }
  __syncthreads();
}

// ---- prologue helpers (256 blocks x 512 threads; identical to R19) --------
__device__ __forceinline__ void stv(float* p, float v) { *p = v; }
__device__ __forceinline__ void stv(__half* p, float v) { *p = __float2half(v); }

template <int J, int N, int CPT, typename OT>
__device__ void matmat(const float* __restrict__ A, const float* __restrict__ B,
                       OT* __restrict__ C) {
  const int tid = threadIdx.x;
  const int r = blockIdx.x * 4 + (tid >> 7);
  const int c0 = tid & 127;
  float acc[CPT];
#pragma unroll
  for (int i = 0; i < CPT; ++i) acc[i] = 0.f;
  const float* ar = A + (size_t)r * J;
#pragma unroll 2
  for (int j = 0; j < J; ++j) {
    float av = ar[j];
    const float* br = B + (size_t)j * N + c0;
#pragma unroll
    for (int i = 0; i < CPT; ++i) acc[i] = fmaf(av, br[i * 128], acc[i]);
  }
  OT* cr = C + (size_t)r * N + c0;
#pragma unroll
  for (int i = 0; i < CPT; ++i) stv(cr + (size_t)i * 128, acc[i]);
}

__device__ void cvt_copy(const float* __restrict__ s, __half* __restrict__ d,
                         int n4) {
  for (int i = (int)(blockIdx.x * 512u + threadIdx.x); i < n4; i += 131072)
    *(unsigned long long*)(d + (size_t)i * 4) = f4h4(*(const float4*)(s + (size_t)i * 4));
}

__device__ void vecmat(const float* __restrict__ v, const float* __restrict__ M,
                       const float* __restrict__ badd, float* __restrict__ outv,
                       int J, int N, int blk0, int nblk) {
  int b = (int)blockIdx.x;
  if (b < blk0 || b >= blk0 + nblk) return;
  int gid = (b - blk0) * 512 + threadIdx.x;
  if (gid >= N) return;
  float acc = 0.f;
#pragma unroll 4
  for (int j = 0; j < J; ++j) acc = fmaf(v[j], M[(size_t)j * N + gid], acc);
  outv[gid] = acc + badd[gid];
}

__device__ void gemv1024(const float* __restrict__ A, const float* __restrict__ W,
                         const float* __restrict__ bias, int K, int relu,
                         float* __restrict__ C, float* __restrict__ C2,
                         float* __restrict__ C3, float* red) {
  const int tid = threadIdx.x;
  const int m = tid & 63, w = tid >> 6;
  const int j = w & 3, hh = w >> 2;
  const int c = blockIdx.x * 4 + j;
  const int kh = K >> 1;
  const float* a = A + m + (hh * kh) * 64;
  const float* wp = W + c + (size_t)(hh * kh) * 1024;
  float acc = 0.f;
#pragma unroll 8
  for (int k = 0; k < kh; ++k) acc = fmaf(a[k * 64], wp[(size_t)k * 1024], acc);
  if (hh) red[j * 64 + m] = acc;
  __syncthreads();
  if (!hh) {
    float v = acc + red[j * 64 + m] + bias[c];
    if (relu) v = fmaxf(v, 0.f);
    C[c * 64 + m] = v;
    if (C2) C2[c * 64 + m] = v;
    if (C3) C3[c * 64 + m] = v;
  }
  __syncthreads();
}

// ---- pin one gru weight tile TRANSPOSED [c][k] swizzled into LDS ----------
// dst: [96][256] halves; byte(c,k) = c*512 + ((k*2) ^ ((c&7)<<4)).
// Coalesced-ish global reads (lanes span consecutive c of one k-row).
__device__ void pin_wT(const __half* __restrict__ W, int k0, int c0,
                       __half* __restrict__ dst) {
  const int tid = threadIdx.x;
#pragma unroll
  for (int i = 0; i < 48; ++i) {
    int idx = tid + i * 512;          // 0..24575
    int k = idx / 96, c = idx - k * 96;
    __half v = W[(size_t)(k0 + k) * 3072 + c0 + c];
    unsigned off = (unsigned)(c * 512 + (((k * 2) ^ ((c & 7) << 4))));
    *(__half*)((char*)dst + off) = v;
  }
}

// ---- GRU matmul (MFMA, pinned transposed weights, fp16 acts) --------------
// Stage acts transposed+swizzled into scratch: at[m][k], byte = m*512 +
// ((k*2)^((m&7)<<4)). 8 waves x 3 tiles (tile = Nt*4+Mt), 8 mfma(K=32) per
// tile. A-frag: lane l -> A[m=Mt*16+(l&15)][k=kk*32+(l>>4)*8 ..+8] (b128).
// B-frag: lane l -> W[c=Nt*16+(l&15)][same k] (b128). D: row m'=Mt*16+
// (l>>4)*4+reg, col=Nt*16+(l&15) -> pack4h -> one 8B store into part16.
__device__ __forceinline__ void gru_mm_p(const __half* __restrict__ A16,
                                         const __half* __restrict__ wpin,
                                         int s, int c0,
                                         __half* __restrict__ part16,
                                         float* __restrict__ scr) {
  const int tid = threadIdx.x;
  __half* at = (__half*)scr;   // [64][256]h swizzled = 32 KB
  {
    const unsigned long long* Ab = (const unsigned long long*)A16;
#pragma unroll
    for (int i = 0; i < 8; ++i) {
      int idx = tid + i * 512;          // u64 index = k*16 + mq
      int k = idx >> 4, mq = idx & 15;
      unsigned long long q = ald64(Ab + idx);
      union { unsigned long long v; __half h[4]; } u; u.v = q;
#pragma unroll
      for (int j = 0; j < 4; ++j) {
        int m = mq * 4 + j;
        unsigned off = (unsigned)(m * 512 + (((k * 2) ^ ((m & 7) << 4))));
        *(__half*)((char*)at + off) = u.h[j];
      }
    }
  }
  __syncthreads();
  const int w = tid >> 6, l = tid & 63;
  const int l15 = l & 15, l4 = l >> 4;
#pragma unroll
  for (int ti = 0; ti < 3; ++ti) {
    const int tile = w + ti * 8;          // 0..23 = Nt*4 + Mt
    const int Mt = tile & 3, Nt = tile >> 2;
    const int ma = Mt * 16 + l15;         // A-frag row
    const int cb = Nt * 16 + l15;         // B-frag col
    f32x4_t acc = {0.f, 0.f, 0.f, 0.f};
#pragma unroll
    for (int kk = 0; kk < 8; ++kk) {
      const int k = kk * 32 + l4 * 8;
      f16x8_t av = *(const f16x8_t*)((const char*)at +
                     (ma * 512 + (((k * 2) ^ ((ma & 7) << 4)))));
      f16x8_t bv = *(const f16x8_t*)((const char*)wpin +
                     (cb * 512 + (((k * 2) ^ ((cb & 7) << 4)))));
      acc = __builtin_amdgcn_mfma_f32_16x16x32_f16(av, bv, acc, 0, 0, 0);
    }
    __half* pb = part16 + ((size_t)s * 3072 + c0 + cb) * 64 + Mt * 16 + l4 * 4;
    ast64((unsigned long long*)pb, pack4h(acc[0], acc[1], acc[2], acc[3]));
  }
  __syncthreads();   // acts buffer reuse safety for next phase
}

// GRU combine: fp16 partials in, fp16 h state out. 256 blocks, 256 thr.
__device__ __forceinline__ void gru_comb(const __half* __restrict__ part16,
                                         const float* __restrict__ bx,
                                         const float* __restrict__ bm,
                                         __half* __restrict__ h16) {
  const int tid = threadIdx.x, bid = blockIdx.x;
  if (tid >= 256) return;
  const int c = bid * 4 + (tid >> 6), m = tid & 63;
  float ra = 0.f, za = 0.f, ia = 0.f, na = 0.f;
#pragma unroll
  for (int s = 0; s < 8; ++s) {
    const __half* ps = part16 + (size_t)s * 3072 * 64;
    ra += aldh(ps + (size_t)c * 64 + m);
    za += aldh(ps + (size_t)(1024 + c) * 64 + m);
    float nv = aldh(ps + (size_t)(2048 + c) * 64 + m);
    if (s < 4) ia += nv; else na += nv;
  }
  float r  = 1.f / (1.f + expf(-(ra + bx[c] + bm[c])));
  float zg = 1.f / (1.f + expf(-(za + bx[1024 + c] + bm[1024 + c])));
  float nn = tanhf(ia + bx[2048 + c] + r * (na + bm[2048 + c]));
  float hp = aldh(h16 + (size_t)c * 64 + m);
  asth(h16 + (size_t)c * 64 + m, (1.f - zg) * nn + zg * hp);
}

// ---- P5 (fp16 acts, VALU; verbatim R19) -----------------------------------
__device__ __forceinline__ void p5_mm(const __half* __restrict__ WhW1,
                                      const __half* __restrict__ Whd,
                                      const __half* __restrict__ h216,
                                      __half* __restrict__ part16,
                                      float* __restrict__ sm) {
  const int tid = threadIdx.x, bid = blockIdx.x;
  const int g = bid >> 3, s = bid & 7;
  const int c0 = g * 40;
  const int k0 = s * 128;

  {  // stage acts (2048 u64)
    const unsigned long long* Ab =
        (const unsigned long long*)(h216 + (size_t)k0 * 64);
    unsigned long long* Sb = (unsigned long long*)sm;
#pragma unroll
    for (int i = 0; i < 4; ++i) Sb[tid + i * 512] = ald64(Ab + tid + i * 512);
  }
  {  // stage weights: 1024 (row,grp) pairs, 5 scalar halves each, padded 8
    __half* Sw = (__half*)(sm + 8192);
#pragma unroll
    for (int r = 0; r < 2; ++r) {
      int i2 = tid + r * 512;
      int row = i2 & 127, grp = i2 >> 7;
      const int gcb = c0 + grp * 5;
      __half* dst = Sw + row * 64 + grp * 8;
#pragma unroll
      for (int j = 0; j < 5; ++j) {
        int gc = gcb + j;
        dst[j] = (gc < 1024) ? WhW1[(size_t)(k0 + row) * 1024 + gc]
                             : Whd[(size_t)(k0 + row) * 256 + (gc - 1024)];
      }
    }
  }
  __syncthreads();

  const int ksub = tid >> 7, u = tid & 127;
  const int mq = u & 15, cg = u >> 4;
  float acc[20];
#pragma unroll
  for (int j = 0; j < 20; ++j) acc[j] = 0.f;
  const __half* ap = (const __half*)sm + (size_t)(ksub * 32) * 64 + mq * 4;
  const __half* wp = (const __half*)(sm + 8192) + (size_t)(ksub * 32) * 64 + cg * 8;
#pragma unroll 4
  for (int k = 0; k < 32; ++k) {
    float4 a4 = h4f(*(const unsigned long long*)(ap + k * 64));
    union { u64x2 v; __half h[8]; } uw;
    uw.v = *(const u64x2*)(wp + k * 64);
#pragma unroll
    for (int cc = 0; cc < 5; ++cc) {
      float wf = __half2float(uw.h[cc]);
      acc[cc * 4 + 0] = fmaf(a4.x, wf, acc[cc * 4 + 0]);
      acc[cc * 4 + 1] = fmaf(a4.y, wf, acc[cc * 4 + 1]);
      acc[cc * 4 + 2] = fmaf(a4.z, wf, acc[cc * 4 + 2]);
      acc[cc * 4 + 3] = fmaf(a4.w, wf, acc[cc * 4 + 3]);
    }
  }
  __syncthreads();
  float* red = sm;   // 4 regions x 2560 floats, layout = col_local*64 + m
  {
    float* rp = red + (size_t)ksub * 2560 + (size_t)cg * 5 * 64 + mq * 4;
#pragma unroll
    for (int cc = 0; cc < 5; ++cc)
      *(float4*)(rp + (size_t)cc * 64) =
          make_float4(acc[cc * 4], acc[cc * 4 + 1], acc[cc * 4 + 2], acc[cc * 4 + 3]);
  }
  __syncthreads();
  {
    __half* pbase = part16 + ((size_t)s * 1280 + c0) * 64;   // 2560 contiguous
#pragma unroll
    for (int ps5 = 0; ps5 < 3; ++ps5) {
      int idx = ps5 * 1024 + tid * 2;
      if (idx < 2560) {
        float2 a0 = *(const float2*)(red + idx);
        float2 a1 = *(const float2*)(red + 2560 + idx);
        float2 a2 = *(const float2*)(red + 5120 + idx);
        float2 a3 = *(const float2*)(red + 7680 + idx);
        float v0 = (a0.x + a1.x) + (a2.x + a3.x);
        float v1 = (a0.y + a1.y) + (a2.y + a3.y);
        ast32((unsigned*)(pbase + idx), pack2h(v0, v1));
      }
    }
  }
}

// P5 combine: t1 (fp16) cols 0..1023 (tid<256), out cols 1024..1279.
__device__ __forceinline__ void p5b(const __half* __restrict__ part16,
                                    const float* __restrict__ bhw1,
                                    const float* __restrict__ bh,
                                    __half* __restrict__ t116,
                                    float* __restrict__ out, int t) {
  const int tid = threadIdx.x, bid = blockIdx.x;
  if (tid < 256) {
    const int c = bid * 4 + (tid >> 6), m = tid & 63;
    float v = 0.f;
#pragma unroll
    for (int s = 0; s < 8; ++s) v += aldh(part16 + ((size_t)s * 1280 + c) * 64 + m);
    asth(t116 + (size_t)c * 64 + m, fmaxf(v + bhw1[c], 0.f));
  } else if (tid < 320) {
    const int m = tid - 256, c2 = bid;
    float v = 0.f;
#pragma unroll
    for (int s = 0; s < 8; ++s)
      v += aldh(part16 + ((size_t)s * 1280 + 1024 + c2) * 64 + m);
    out[(size_t)(m * TSTEP + t) * LATD + c2] = v + bh[c2];
  }
}

// P6 (fp16 acts, VALU; verbatim R19).
__device__ __forceinline__ void p6_mm(const __half* __restrict__ w2h,
                                      const __half* __restrict__ t116,
                                      __half* __restrict__ part16,
                                      float* __restrict__ sm) {
  const int tid = threadIdx.x;
  const int bid = blockIdx.x;
  const int g = bid >> 3, s = bid & 7;
  const int c0 = g * 32;
  const int k0 = s * 128;

  {  // stage acts (2048 u64)
    const unsigned long long* Ab =
        (const unsigned long long*)(t116 + (size_t)k0 * 64);
    unsigned long long* Sb = (unsigned long long*)sm;
#pragma unroll
    for (int i = 0; i < 4; ++i) Sb[tid + i * 512] = ald64(Ab + tid + i * 512);
  }
  {  // stage weights: 1024 8B-chunks (4 halves each)
    unsigned long long* Sw = (unsigned long long*)(sm + 8192);
#pragma unroll
    for (int i = 0; i < 2; ++i) {
      int q = tid + i * 512;
      int k = q >> 3, cq = q & 7;
      Sw[k * 8 + cq] =
          *(const unsigned long long*)(w2h + (size_t)(k0 + k) * 1024 + c0 + cq * 4);
    }
  }
  __syncthreads();

  const int ksub = tid >> 7, u = tid & 127;
  const int mq = u & 15, cg = u >> 4;
  float acc[16];
#pragma unroll
  for (int j = 0; j < 16; ++j) acc[j] = 0.f;
  const __half* ap = (const __half*)sm + (size_t)(ksub * 32) * 64 + mq * 4;
  const __half* wp = (const __half*)(sm + 8192) + (size_t)(ksub * 32) * 32 + cg * 4;
#pragma unroll 4
  for (int k = 0; k < 32; ++k) {
    float4 a4 = h4f(*(const unsigned long long*)(ap + k * 64));
    union { unsigned long long v; __half h[4]; } ub;
    ub.v = *(const unsigned long long*)(wp + k * 32);
#pragma unroll
    for (int c = 0; c < 4; ++c) {
      float wf = __half2float(ub.h[c]);
      acc[c * 4 + 0] = fmaf(a4.x, wf, acc[c * 4 + 0]);
      acc[c * 4 + 1] = fmaf(a4.y, wf, acc[c * 4 + 1]);
      acc[c * 4 + 2] = fmaf(a4.z, wf, acc[c * 4 + 2]);
      acc[c * 4 + 3] = fmaf(a4.w, wf, acc[c * 4 + 3]);
    }
  }
  __syncthreads();
  float* red = sm;   // 4 regions x 2048 floats
  {
    float* rp = red + (size_t)ksub * 2048 + (size_t)cg * 4 * 64 + mq * 4;
#pragma unroll
    for (int c = 0; c < 4; ++c)
      *(float4*)(rp + (size_t)c * 64) =
          make_float4(acc[c * 4], acc[c * 4 + 1], acc[c * 4 + 2], acc[c * 4 + 3]);
  }
  __syncthreads();
  {
    __half* pbase = part16 + ((size_t)s * 1024 + c0) * 64;   // 2048 contiguous
#pragma unroll
    for (int ps5 = 0; ps5 < 2; ++ps5) {
      int idx = ps5 * 1024 + tid * 2;
      float2 a0 = *(const float2*)(red + idx);
      float2 a1 = *(const float2*)(red + 2048 + idx);
      float2 a2 = *(const float2*)(red + 4096 + idx);
      float2 a3 = *(const float2*)(red + 6144 + idx);
      float v0 = (a0.x + a1.x) + (a2.x + a3.x);
      float v1 = (a0.y + a1.y) + (a2.y + a3.y);
      ast32((unsigned*)(pbase + idx), pack2h(v0, v1));
    }
  }
}

__device__ __forceinline__ void p6b(const __half* __restrict__ part16,
                                    const float* __restrict__ b2,
                                    __half* __restrict__ gin16) {
  const int tid = threadIdx.x, bid = blockIdx.x;
  if (tid >= 256) return;
  const int c = bid * 4 + (tid >> 6), m = tid & 63;
  float v = 0.f;
#pragma unroll
  for (int s = 0; s < 8; ++s) v += aldh(part16 + ((size_t)s * 1024 + c) * 64 + m);
  asth(gin16 + (size_t)c * 64 + m, fmaxf(v + b2[c], 0.f));
}

__global__ __launch_bounds__(512, 1) void persist(P p) {
  cg::grid_group grid = cg::this_grid();
  // 160 KB: pinned gru1 [c][k] swz [0,12288) f | gru2 [12288,24576) f |
  // scratch [24576,40960) = 64 KB (gru acts [64][256]h swz = 8192 f; p5/p6).
  __shared__ float sm[40960];
  float* const SCR = sm + 24576;
  unsigned ep = 0;

  // ---- prologue (5 slow cg syncs flush prologue's normal stores) ----
  if (blockIdx.x == 0) {
    for (int i = threadIdx.x; i < 1024; i += 512) p.bar[i] = 0u;
  }
  if (threadIdx.x < 64) {  // z transpose -> h1 region (consumed pre-overwrite)
    int i = blockIdx.x * 64 + threadIdx.x;
    int m = i >> 8, l = i & 255;
    p.h1[l * 64 + m] = p.z[i];
  }
  matmat<1024, 1024, 8>(p.Wv, p.Wo, p.part);            // Wvo (fp32 temp)
  vecmat(p.bh, p.w1, p.b1, p.bhw1, 256, 1024, 0, 2);
  vecmat(p.bv, p.Wo, p.bo, p.bvo, 1024, 1024, 2, 2);
  cvt_copy(p.Whh0, p.Whh0h, 786432);                    // raw weights -> fp16
  cvt_copy(p.Wih1, p.Wih1h, 786432);
  cvt_copy(p.Whh1, p.Whh1h, 786432);
  cvt_copy(p.w2,   p.w2h,   262144);
  cvt_copy(p.Wh,   p.Whh,   65536);
  grid.sync();
  matmat<1024, 3072, 24>(p.part, p.Wih0, p.Wvoihh);     // Wvoih -> fp16 direct
  matmat<256, 1024, 8>(p.Wh, p.w1, p.WhW1h);            // WhW1 -> fp16 direct
  vecmat(p.bvo, p.Wih0, p.bih0, p.bfold, 1024, 3072, 0, 6);
  grid.sync();
  gemv1024(p.h1, p.w1, p.b1, 256, 1, p.t1, nullptr, nullptr, SCR);
  grid.sync();
  gemv1024(p.t1, p.w2, p.b2, 1024, 0, p.h1, p.h2, p.gin, SCR);
  grid.sync();
  // convert initial states fp32 -> fp16 loop buffers (Wvo temp long dead)
  for (int i = (int)(blockIdx.x * 512u + threadIdx.x); i < 16384; i += 131072) {
    float4 v = *(const float4*)(p.h1 + (size_t)i * 4);
    unsigned long long q = f4h4(v);
    *(unsigned long long*)(p.h116 + (size_t)i * 4) = q;
    *(unsigned long long*)(p.h216 + (size_t)i * 4) = q;
    *(unsigned long long*)(p.gin16 + (size_t)i * 4) = q;
  }
  grid.sync();

  // ---- pin gru weight tiles transposed once (reused for all 128 steps) ----
  const int s0 = blockIdx.x & 7, g0 = blockIdx.x >> 3;
  const int c00 = g0 * 96, k00 = (s0 & 3) * 256;
  pin_wT((s0 < 4 ? p.Wvoihh : p.Whh0h), k00, c00, (__half*)sm);
  pin_wT((s0 < 4 ? p.Wih1h  : p.Whh1h), k00, c00, (__half*)(sm + 12288));
  __syncthreads();

  // ---- time loop: 8 fence-free phases/step ----
  for (int t = 0; t < TSTEP; ++t) {
    gru_mm_p((s0 < 4 ? p.gin16 : p.h116) + (size_t)k00 * 64,
             (const __half*)sm, s0, c00, p.part16, SCR);
    fastbar(p.bar, ep);
    gru_comb(p.part16, p.bfold, p.bhh0, p.h116);          fastbar(p.bar, ep);
    gru_mm_p((s0 < 4 ? p.h116 : p.h216) + (size_t)k00 * 64,
             (const __half*)(sm + 12288), s0, c00, p.part16, SCR);
    fastbar(p.bar, ep);
    gru_comb(p.part16, p.bih1, p.bhh1, p.h216);           fastbar(p.bar, ep);
    p5_mm(p.WhW1h, p.Whh, p.h216, p.part16, SCR);         fastbar(p.bar, ep);
    p5b(p.part16, p.bhw1, p.bh, p.t116, p.out, t);        fastbar(p.bar, ep);
    p6_mm(p.w2h, p.t116, p.part16, SCR);                  fastbar(p.bar, ep);
    p6b(p.part16, p.b2, p.gin16);                         fastbar(p.bar, ep);
  }
}

// ---------------------------------------------------------------------------
// Fallback path (round-2 verified multi-kernel, fp32 — unchanged).
// ---------------------------------------------------------------------------
__global__ void fb_transpose(const float* __restrict__ z, float* __restrict__ zT) {
  int i = blockIdx.x * 256 + threadIdx.x;
  int m = i >> 8, l = i & 255;
  zT[l * 64 + m] = z[i];
}
__global__ void fb_copy2(const float* __restrict__ s, float* __restrict__ d1,
                         float* __restrict__ d2) {
  int i = blockIdx.x * 256 + threadIdx.x;
  float v = s[i]; d1[i] = v; d2[i] = v;
}
template <int ACT>
__global__ void fb_gemm(const float* __restrict__ A_T, const float* __restrict__ W,
                        const float* __restrict__ bias, float* __restrict__ C_T,
                        int K, int N, float* __restrict__ outp, int tstep) {
  const int m = threadIdx.x & 63;
  const int wv = threadIdx.x >> 6;
  const int c = blockIdx.x * 4 + wv;
  float acc0 = 0.f, acc1 = 0.f;
  const float* ap = A_T + m;
  const float* wp = W + c;
#pragma unroll 4
  for (int k = 0; k + 1 < K; k += 2) {
    acc0 = fmaf(ap[k * 64], wp[(size_t)k * N], acc0);
    acc1 = fmaf(ap[(k + 1) * 64], wp[(size_t)(k + 1) * N], acc1);
  }
  float v0 = acc0 + acc1 + bias[c];
  if (ACT) v0 = fmaxf(v0, 0.f);
  C_T[c * 64 + m] = v0;
  if (outp != nullptr) outp[(size_t)(m * TSTEP + tstep) * LATD + c] = v0;
}
__global__ void fb_gru(const float* __restrict__ xT, const float* __restrict__ hT,
                       const float* __restrict__ Wih, const float* __restrict__ Whh,
                       const float* __restrict__ bih, const float* __restrict__ bhh,
                       float* __restrict__ hnT) {
  const int m = threadIdx.x & 63;
  const int wv = threadIdx.x >> 6;
  const int c = blockIdx.x * 4 + wv;
  float racc = 0, zacc = 0, iacc = 0, nacc = 0;
  const float* xp = xT + m;
  const float* hp = hT + m;
  const float* wi = Wih + c;
  const float* wh = Whh + c;
#pragma unroll 2
  for (int k = 0; k < 1024; ++k) {
    float a = xp[k * 64];
    float h = hp[k * 64];
    const float* wik = wi + (size_t)k * 3072;
    const float* whk = wh + (size_t)k * 3072;
    racc = fmaf(a, wik[0], racc); racc = fmaf(h, whk[0], racc);
    zacc = fmaf(a, wik[1024], zacc); zacc = fmaf(h, whk[1024], zacc);
    iacc = fmaf(a, wik[2048], iacc);
    nacc = fmaf(h, whk[2048], nacc);
  }
  float r = 1.f / (1.f + expf(-(racc + bih[c] + bhh[c])));
  float zg = 1.f / (1.f + expf(-(zacc + bih[1024 + c] + bhh[1024 + c])));
  float nn = tanhf(iacc + bih[2048 + c] + r * (nacc + bhh[2048 + c]));
  hnT[c * 64 + m] = (1.f - zg) * nn + zg * hT[c * 64 + m];
}

extern "C" void kernel_launch(void* const* d_in, const int* in_sizes, int n_in,
                              void* d_out, int out_size, void* d_ws, size_t ws_size,
                              hipStream_t stream) {
  const float* z_start = (const float*)d_in[0];
  const float* w1 = (const float*)d_in[2];
  const float* b1 = (const float*)d_in[3];
  const float* w2 = (const float*)d_in[4];
  const float* b2 = (const float*)d_in[5];
  const float* Wv = (const float*)d_in[10];
  const float* bv = (const float*)d_in[11];
  const float* Wo = (const float*)d_in[12];
  const float* bo = (const float*)d_in[13];
  const float* Wih0 = (const float*)d_in[14];
  const float* Whh0 = (const float*)d_in[15];
  const float* bih0 = (const float*)d_in[16];
  const float* bhh0 = (const float*)d_in[17];
  const float* Wih1 = (const float*)d_in[18];
  const float* Whh1 = (const float*)d_in[19];
  const float* bih1 = (const float*)d_in[20];
  const float* bhh1 = (const float*)d_in[21];
  const float* Wh = (const float*)d_in[22];
  const float* bh = (const float*)d_in[23];
  float* out = (float*)d_out;
  float* ws = (float*)d_ws;

  // floats: 4x1572864 (fp16 wbufs) + part 1572864 (Wvo fp32 temp in
  // prologue; loop: fp16 partials [0..786432)f + fp16 acts [786432..917504)f)
  // + 524288x2 (WhW1_h,w2_h) + 131072 (Wh_h) + 4x65536 fp32 acts (prologue)
  // + 5120 small + 1024 bar
  const size_t need = (size_t)9312256 * 4;
  if (ws_size >= need) {
    P p;
    p.z = z_start; p.w1 = w1; p.b1 = b1; p.w2 = w2; p.b2 = b2;
    p.Wv = Wv; p.bv = bv; p.Wo = Wo; p.bo = bo;
    p.Wih0 = Wih0; p.Whh0 = Whh0; p.bih0 = bih0; p.bhh0 = bhh0;
    p.Wih1 = Wih1; p.Whh1 = Whh1; p.bih1 = bih1; p.bhh1 = bhh1;
    p.Wh = Wh; p.bh = bh; p.out = out;
    float* q = ws;
    p.Wvoihh = (__half*)q; q += 1572864;   // 1024x3072 halves
    p.Whh0h  = (__half*)q; q += 1572864;
    p.Wih1h  = (__half*)q; q += 1572864;
    p.Whh1h  = (__half*)q; q += 1572864;
    p.WhW1h  = (__half*)q; q += 524288;    // 1024x1024 halves
    p.Whh    = (__half*)q; q += 131072;    // 1024x256 halves
    p.w2h    = (__half*)q; q += 524288;
    p.part = q; q += 1572864;   // Wvo fp32 temp / loop fp16 parts + acts
    p.part16 = (__half*)p.part;
    p.gin16 = (__half*)(p.part + 786432);
    p.h116  = (__half*)(p.part + 819200);
    p.h216  = (__half*)(p.part + 851968);
    p.t116  = (__half*)(p.part + 884736);
    p.gin = q; q += 65536;
    p.h1 = q; q += 65536;       // also zT during prologue
    p.h2 = q; q += 65536;
    p.t1 = q; q += 65536;
    p.bvo = q; q += 1024;
    p.bfold = q; q += 3072;
    p.bhw1 = q; q += 1024;
    p.bar = (unsigned*)q; q += 1024;
    void* args[] = { &p };
    hipError_t e = hipLaunchCooperativeKernel((const void*)persist, dim3(256),
                                              dim3(512), args, 0, stream);
    if (e == hipSuccess) return;
  }

  // -------- fallback: verified round-2 path --------
  float* zsT = ws;
  float* vT = zsT + 16384;
  float* xaT = vT + 65536;
  float* t1T = xaT + 65536;
  float* ginT = t1T + 65536;
  float* nzT = ginT + 65536;
  float* h1T = nzT + 16384;
  float* h2T = h1T + 2 * 65536;

  fb_transpose<<<64, 256, 0, stream>>>(z_start, zsT);
  fb_gemm<1><<<256, 256, 0, stream>>>(zsT, w1, b1, t1T, 256, 1024, nullptr, 0);
  fb_gemm<0><<<256, 256, 0, stream>>>(t1T, w2, b2, h1T, 1024, 1024, nullptr, 0);
  fb_copy2<<<256, 256, 0, stream>>>(h1T, h2T, ginT);
  for (int t = 0; t < TSTEP; ++t) {
    float* h1p = h1T + (t & 1) * 65536;
    float* h1n = h1T + ((t + 1) & 1) * 65536;
    float* h2p = h2T + (t & 1) * 65536;
    float* h2n = h2T + ((t + 1) & 1) * 65536;
    fb_gemm<0><<<256, 256, 0, stream>>>(ginT, Wv, bv, vT, 1024, 1024, nullptr, 0);
    fb_gemm<0><<<256, 256, 0, stream>>>(vT, Wo, bo, xaT, 1024, 1024, nullptr, 0);
    fb_gru<<<256, 256, 0, stream>>>(xaT, h1p, Wih0, Whh0, bih0, bhh0, h1n);
    fb_gru<<<256, 256, 0, stream>>>(h1n, h2p, Wih1, Whh1, bih1, bhh1, h2n);
    fb_gemm<0><<<64, 256, 0, stream>>>(h2n, Wh, bh, nzT, 1024, 256, out, t);
    fb_gemm<1><<<256, 256, 0, stream>>>(nzT, w1, b1, t1T, 256, 1024, nullptr, 0);
    fb_gemm<1><<<256, 256, 0, stream>>>(t1T, w2, b2, ginT, 1024, 1024, nullptr, 0);
  }
}